// Round 12
// baseline (1495.283 us; speedup 1.0000x reference)
//
#include <hip/hip_runtime.h>
#include <hip/hip_bf16.h>
#include <math.h>

#define TT 2048
#define DD 2048
#define NH 16
#define DNN 128
#define DRR 64
#define DVV 128
#define QLL 768
#define KVLL 512
#define HII 16
#define DII 128
#define TOPKN 256
#define NEE 8
#define MII 1024
#define QKVW 1488            // 1344 qkv + 128 ik + 16 iw
#define QW 5120              // 3072 q + 2048 iq
#define EPSF 1e-6f
#define NEGF (-1e30f)
#define SCALEF 0.07216878364870323f
#define IQSCALE 0.08838834764831845f
#define LOG1E4 9.210340371976184f
#define CHK 512              // attention token chunk

typedef unsigned short u16;
typedef __attribute__((ext_vector_type(8))) short s8v;
typedef __attribute__((ext_vector_type(4))) float f4v;

__device__ inline void split_bf16(float x, u16& h, u16& l) {
  __hip_bfloat16 bh_ = __float2bfloat16(x);
  float hf = __bfloat162float(bh_);
  __hip_bfloat16 bl_ = __float2bfloat16(x - hf);
  h = *(u16*)&bh_; l = *(u16*)&bl_;
}
__device__ inline u16 rnd_bf16(float x) {
  __hip_bfloat16 b = __float2bfloat16(x);
  return *(u16*)&b;
}
__device__ inline float b2f(u16 h) { return __uint_as_float(((unsigned)h) << 16); }

// ---------------------------------------------------------------- RMS norm (f32 and/or bf16 hi(+lo) outputs)
__global__ __launch_bounds__(256) void rms_kernel(
    const float* __restrict__ src, int sstride, int width,
    const float* __restrict__ w,
    float* __restrict__ dstf, int dfstride,
    u16* __restrict__ dsthi, u16* __restrict__ dstlo, int dhstride)
{
  int t = blockIdx.x, tid = threadIdx.x;
  const float* x = src + (size_t)t * sstride;
  float ss = 0.f;
  for (int i = tid; i < width; i += 256) { float v = x[i]; ss += v * v; }
  for (int off = 32; off; off >>= 1) ss += __shfl_down(ss, off, 64);
  __shared__ float red[4];
  __shared__ float scale_sh;
  if ((tid & 63) == 0) red[tid >> 6] = ss;
  __syncthreads();
  if (tid == 0) {
    float tot = red[0] + red[1] + red[2] + red[3];
    scale_sh = rsqrtf(tot / (float)width + EPSF);
  }
  __syncthreads();
  float sc2 = scale_sh;
  for (int i = tid; i < width; i += 256) {
    float y = x[i] * sc2 * w[i];
    if (dstf) dstf[(size_t)t * dfstride + i] = y;
    if (dsthi) {
      if (dstlo) {
        u16 h, l; split_bf16(y, h, l);
        dsthi[(size_t)t * dhstride + i] = h;
        dstlo[(size_t)t * dhstride + i] = l;
      } else {
        dsthi[(size_t)t * dhstride + i] = rnd_bf16(y);
      }
    }
  }
}

// ---------------------------------------------------------------- residual + RMS + bf16 hi/lo
__global__ __launch_bounds__(256) void res_rms(
    const float* __restrict__ o, const float* __restrict__ hid,
    const float* __restrict__ w,
    float* __restrict__ resid, u16* __restrict__ dhi, u16* __restrict__ dlo)
{
  int t = blockIdx.x, tid = threadIdx.x;
  long base = (long)t * DD;
  float xv[8];
  float ss = 0.f;
#pragma unroll
  for (int j = 0; j < 8; ++j) {
    int i = j * 256 + tid;
    float v = o[base + i] + hid[base + i];
    xv[j] = v; resid[base + i] = v; ss += v * v;
  }
  for (int off = 32; off; off >>= 1) ss += __shfl_down(ss, off, 64);
  __shared__ float red[4];
  __shared__ float scale_sh;
  if ((tid & 63) == 0) red[tid >> 6] = ss;
  __syncthreads();
  if (tid == 0) scale_sh = rsqrtf((red[0] + red[1] + red[2] + red[3]) / (float)DD + EPSF);
  __syncthreads();
  float sc2 = scale_sh;
#pragma unroll
  for (int j = 0; j < 8; ++j) {
    int i = j * 256 + tid;
    float y = xv[j] * sc2 * w[i];
    u16 h, l; split_bf16(y, h, l);
    dhi[base + i] = h; dlo[base + i] = l;
  }
}

// ---------------------------------------------------------------- LayerNorm + RoPE for index_k -> bf16 hi/lo (strided src)
__global__ __launch_bounds__(128) void ln_rope_ik(
    const float* __restrict__ src, int sstride,
    const float* __restrict__ w, const float* __restrict__ b,
    const int* __restrict__ pos, u16* __restrict__ dhi, u16* __restrict__ dlo)
{
  int t = blockIdx.x, tid = threadIdx.x;
  __shared__ float rowv[128];
  __shared__ float red[2];
  float v = src[(size_t)t * sstride + tid];
  float s = v;
  for (int off = 32; off; off >>= 1) s += __shfl_down(s, off, 64);
  if ((tid & 63) == 0) red[tid >> 6] = s;
  __syncthreads();
  float mu = (red[0] + red[1]) * (1.f / 128.f);
  __syncthreads();
  float dlt = v - mu;
  float s2 = dlt * dlt;
  for (int off = 32; off; off >>= 1) s2 += __shfl_down(s2, off, 64);
  if ((tid & 63) == 0) red[tid >> 6] = s2;
  __syncthreads();
  float var = (red[0] + red[1]) * (1.f / 128.f);
  float yv = dlt * rsqrtf(var + EPSF) * w[tid] + b[tid];
  rowv[tid] = yv;
  __syncthreads();
  if (tid < 64) {
    float x1 = rowv[tid], x2 = rowv[tid + 64];
    float p = (float)pos[t];
    float invf = expf(-(2.f * tid / 128.f) * LOG1E4);
    float f = p * invf;
    float cf = cosf(f), sf = sinf(f);
    float y1 = x1 * cf - x2 * sf;
    float y2 = x2 * cf + x1 * sf;
    u16 h1, l1, h2, l2;
    split_bf16(y1, h1, l1); split_bf16(y2, h2, l2);
    long base = (size_t)t * DII + tid;
    dhi[base] = h1; dlo[base] = l1;
    dhi[base + 64] = h2; dlo[base + 64] = l2;
  }
}

// k_pe rope -> kvb bf16 (cols 512..576); qkvx row stride QKVW
__global__ void rope_kpe(const float* __restrict__ qkv, const int* __restrict__ pos, u16* __restrict__ kvb)
{
  int t = blockIdx.x, tid = threadIdx.x;
  if (tid < 32) {
    const float* x = qkv + (size_t)t * QKVW + QLL + KVLL;
    float x1 = x[tid], x2 = x[tid + 32];
    float p = (float)pos[t];
    float invf = expf(-(2.f * tid / 64.f) * LOG1E4);
    float f = p * invf, cf = cosf(f), sf = sinf(f);
    kvb[(long)t * 576 + 512 + tid]      = rnd_bf16(x1 * cf - x2 * sf);
    kvb[(long)t * 576 + 512 + tid + 32] = rnd_bf16(x2 * cf + x1 * sf);
  }
}

// q_pe rope IN-PLACE on qfull (row stride QW, head stride 192, pe at +128)
__global__ void rope_qpe(float* __restrict__ q, const int* __restrict__ pos)
{
  int t = blockIdx.x, tid = threadIdx.x;  // 512 threads
  int h = tid >> 5, j = tid & 31;
  float* x = q + (size_t)t * QW + h * 192 + 128;
  float x1 = x[j], x2 = x[j + 32];
  float p = (float)pos[t];
  float invf = expf(-(2.f * j / 64.f) * LOG1E4);
  float f = p * invf, cf = cosf(f), sf = sinf(f);
  x[j]      = x1 * cf - x2 * sf;
  x[j + 32] = x2 * cf + x1 * sf;
}

// index_q rope + scale + split to bf16 hi/lo; iq at qfull cols 3072+, stride QW
__global__ __launch_bounds__(256) void rope_iq_cvt(
    const float* __restrict__ q, const int* __restrict__ pos,
    u16* __restrict__ dhi, u16* __restrict__ dlo)
{
  int t = blockIdx.x, tid = threadIdx.x;
  float p = (float)pos[t];
#pragma unroll
  for (int r = 0; r < 4; ++r) {
    int e = r * 256 + tid;
    int h = e >> 6, j = e & 63;
    long src = (long)t * QW + 3072 + h * 128 + j;
    long dst = (long)t * 2048 + h * 128 + j;
    float x1 = q[src], x2 = q[src + 64];
    float invf = expf(-(2.f * j / 128.f) * LOG1E4);
    float f = p * invf, cf = cosf(f), sf = sinf(f);
    float y1 = (x1 * cf - x2 * sf) * IQSCALE;
    float y2 = (x2 * cf + x1 * sf) * IQSCALE;
    u16 h1, l1, h2, l2;
    split_bf16(y1, h1, l1); split_bf16(y2, h2, l2);
    dhi[dst] = h1; dlo[dst] = l1;
    dhi[dst + 64] = h2; dlo[dst + 64] = l2;
  }
}

// q_nope [T][H][128] from qfull [T][QW] -> bf16 hi/lo
__global__ __launch_bounds__(256) void cvt_qnope(
    const float* __restrict__ q, u16* __restrict__ hi, u16* __restrict__ lo)
{
  int t = blockIdx.x;
  int e = threadIdx.x * 8;
  int h = e >> 7, d = e & 127;
  const float* src = q + (long)t * QW + h * 192 + d;
  float4 a = *(const float4*)src;
  float4 b = *(const float4*)(src + 4);
  ushort4 h0, l0, h1, l1;
  split_bf16(a.x, h0.x, l0.x); split_bf16(a.y, h0.y, l0.y);
  split_bf16(a.z, h0.z, l0.z); split_bf16(a.w, h0.w, l0.w);
  split_bf16(b.x, h1.x, l1.x); split_bf16(b.y, h1.y, l1.y);
  split_bf16(b.z, h1.z, l1.z); split_bf16(b.w, h1.w, l1.w);
  long ob = (long)t * 2048 + e;
  *(ushort4*)(hi + ob) = h0; *(ushort4*)(hi + ob + 4) = h1;
  *(ushort4*)(lo + ob) = l0; *(ushort4*)(lo + ob + 4) = l1;
}

// ---------------------------------------------------------------- weights [Z][K][N] f32 -> [Z][N][K] bf16 hi(+lo)
__global__ __launch_bounds__(256) void cvt_wT(
    const float* __restrict__ W, u16* __restrict__ hiT, u16* __restrict__ loT, int K, int N)
{
  int z = blockIdx.z;
  const float* in = W + (long)z * K * N;
  u16* ho = hiT + (long)z * K * N;
  u16* lo2 = loT ? loT + (long)z * K * N : nullptr;
  int k0 = blockIdx.y * 32, n0 = blockIdx.x * 32;
  __shared__ float tile[32][33];
  int r = threadIdx.x >> 3, c4 = (threadIdx.x & 7) * 4;
  float4 v = *(const float4*)(in + (long)(k0 + r) * N + n0 + c4);
  tile[r][c4] = v.x; tile[r][c4 + 1] = v.y; tile[r][c4 + 2] = v.z; tile[r][c4 + 3] = v.w;
  __syncthreads();
  float a0 = tile[c4 + 0][r], a1 = tile[c4 + 1][r], a2 = tile[c4 + 2][r], a3 = tile[c4 + 3][r];
  ushort4 h, l;
  split_bf16(a0, h.x, l.x);
  split_bf16(a1, h.y, l.y);
  split_bf16(a2, h.z, l.z);
  split_bf16(a3, h.w, l.w);
  long ob = (long)(n0 + r) * K + k0 + c4;
  *(ushort4*)(ho + ob) = h;
  if (lo2) *(ushort4*)(lo2 + ob) = l;
}

// small-N weight transpose with scale
__global__ void cvt_wT_small(const float* __restrict__ W, u16* __restrict__ hiT, u16* __restrict__ loT,
                             int K, int N, float scale)
{
  int i = blockIdx.x * 256 + threadIdx.x;
  if (i >= K * N) return;
  int n = i / K, k = i - n * K;
  float v = W[(long)k * N + n] * scale;
  u16 h, l; split_bf16(v, h, l);
  hiT[i] = h; loT[i] = l;
}

// ---------------------------------------------------------------- split-bf16 MFMA GEMM; BT pre-transposed [N][K].
// TERMS: 3 = AhBh+AhBl+AlBh (≈f32) ; 1 = AhBh
// OUTMODE: 0 = f32 ; 1 = split hi/lo ; 2 = atomicAdd scatter C[crows[row]] += cw[row]*v
// KS: split-K factor (OUTMODE 0 only); KS>1 uses atomicAdd into pre-zeroed C.
template<int TERMS, int OUTMODE, int KS = 1>
__global__ __launch_bounds__(256) void gemm_bx2(
    const u16* __restrict__ Ahi, const u16* __restrict__ Alo, int lda, long astride,
    const u16* __restrict__ BThi, const u16* __restrict__ BTlo, long bstride,
    float* __restrict__ C, u16* __restrict__ Chi, u16* __restrict__ Clo, int ldc, long cstride,
    int M, int N, int K,
    const int* __restrict__ rowlist, const int* __restrict__ offs, const int* __restrict__ cnts,
    const int* __restrict__ crows, const float* __restrict__ cw)
{
  int zz = blockIdx.z;
  int ksp = (KS > 1) ? (zz % KS) : 0;
  int z = (KS > 1) ? (zz / KS) : zz;
  Ahi += (long)z * astride;
  BThi += (long)z * bstride;
  if (TERMS == 3) { Alo += (long)z * astride; BTlo += (long)z * bstride; }
  if (OUTMODE == 1) { Chi += (long)z * cstride; Clo += (long)z * cstride; }
  else { C += (long)z * cstride; }
  int moff = 0, Mloc = M;
  if (offs) { moff = offs[z]; Mloc = cnts[z]; }
  int m0 = blockIdx.y * 128;
  if (m0 >= Mloc) return;
  int n0 = blockIdx.x * 128;
  int tid = threadIdx.x;

  __shared__ u16 Ah[128][40];
  __shared__ u16 Bh[128][40];
  __shared__ u16 Al[TERMS == 3 ? 128 : 1][40];
  __shared__ u16 Bl[TERMS == 3 ? 128 : 1][40];

  int r0 = tid >> 2, c0 = (tid & 3) * 8;
  int r1 = 64 + r0, c1 = c0;

  long aoff0 = -1, aoff1 = -1;
  {
    int g0 = moff + m0 + r0;
    int g1 = moff + m0 + r1;
    if (m0 + r0 < Mloc) aoff0 = (long)(rowlist ? rowlist[g0] : g0) * lda;
    if (m0 + r1 < Mloc) aoff1 = (long)(rowlist ? rowlist[g1] : g1) * lda;
  }
  long boff0 = (n0 + r0 < N) ? (long)(n0 + r0) * K : -1;
  long boff1 = (n0 + r1 < N) ? (long)(n0 + r1) * K : -1;

  f4v acc[4][4];
#pragma unroll
  for (int i = 0; i < 4; ++i)
#pragma unroll
    for (int j = 0; j < 4; ++j) acc[i][j] = (f4v){0.f, 0.f, 0.f, 0.f};

  int wid = tid >> 6, lane = tid & 63;
  int wr = wid >> 1, wc = wid & 1;
  int frow = lane & 15, koct = (lane >> 4) * 8;

  int kbeg = (KS > 1) ? (K / KS) * ksp : 0;
  int kend = (KS > 1) ? kbeg + K / KS : K;
  for (int kt = kbeg; kt < kend; kt += 32) {
    uint4 zzv = make_uint4(0, 0, 0, 0);
    uint4 ah0 = zzv, ah1 = zzv, bh0 = zzv, bh1 = zzv;
    uint4 al0 = zzv, al1 = zzv, bl0 = zzv, bl1 = zzv;
    if (aoff0 >= 0) ah0 = *(const uint4*)(Ahi + aoff0 + kt + c0);
    if (aoff1 >= 0) ah1 = *(const uint4*)(Ahi + aoff1 + kt + c1);
    if (boff0 >= 0) bh0 = *(const uint4*)(BThi + boff0 + kt + c0);
    if (boff1 >= 0) bh1 = *(const uint4*)(BThi + boff1 + kt + c1);
    if (TERMS == 3) {
      if (aoff0 >= 0) al0 = *(const uint4*)(Alo + aoff0 + kt + c0);
      if (aoff1 >= 0) al1 = *(const uint4*)(Alo + aoff1 + kt + c1);
      if (boff0 >= 0) bl0 = *(const uint4*)(BTlo + boff0 + kt + c0);
      if (boff1 >= 0) bl1 = *(const uint4*)(BTlo + boff1 + kt + c1);
    }
    __syncthreads();
    *(uint4*)&Ah[r0][c0] = ah0;
    *(uint4*)&Ah[r1][c1] = ah1;
    *(uint4*)&Bh[r0][c0] = bh0;
    *(uint4*)&Bh[r1][c1] = bh1;
    if (TERMS == 3) {
      *(uint4*)&Al[r0][c0] = al0;
      *(uint4*)&Al[r1][c1] = al1;
      *(uint4*)&Bl[r0][c0] = bl0;
      *(uint4*)&Bl[r1][c1] = bl1;
    }
    __syncthreads();

    s8v af_h[4], af_l[4];
#pragma unroll
    for (int i = 0; i < 4; ++i) {
      af_h[i] = *(const s8v*)&Ah[wr * 64 + i * 16 + frow][koct];
      if (TERMS == 3) af_l[i] = *(const s8v*)&Al[wr * 64 + i * 16 + frow][koct];
    }
#pragma unroll
    for (int j = 0; j < 4; ++j) {
      s8v bf_h = *(const s8v*)&Bh[wc * 64 + j * 16 + frow][koct];
      s8v bf_l;
      if (TERMS == 3) bf_l = *(const s8v*)&Bl[wc * 64 + j * 16 + frow][koct];
#pragma unroll
      for (int i = 0; i < 4; ++i) {
        acc[i][j] = __builtin_amdgcn_mfma_f32_16x16x32_bf16(af_h[i], bf_h, acc[i][j], 0, 0, 0);
        if (TERMS == 3) {
          acc[i][j] = __builtin_amdgcn_mfma_f32_16x16x32_bf16(af_h[i], bf_l, acc[i][j], 0, 0, 0);
          acc[i][j] = __builtin_amdgcn_mfma_f32_16x16x32_bf16(af_l[i], bf_h, acc[i][j], 0, 0, 0);
        }
      }
    }
  }

  // C/D layout: col = lane&15, row = (lane>>4)*4 + reg
#pragma unroll
  for (int i = 0; i < 4; ++i) {
    int gmb = m0 + wr * 64 + i * 16 + (lane >> 4) * 4;
#pragma unroll
    for (int j = 0; j < 4; ++j) {
      int gn = n0 + wc * 64 + j * 16 + (lane & 15);
      if (gn >= N) continue;
#pragma unroll
      for (int r = 0; r < 4; ++r) {
        int gm = gmb + r;
        if (gm >= Mloc) continue;
        float v = acc[i][j][r];
        long cidx = (long)(moff + gm) * ldc + gn;
        if (OUTMODE == 0) {
          if (KS > 1) atomicAdd(&C[cidx], v);
          else C[cidx] = v;
        } else if (OUTMODE == 1) {
          u16 hh, ll; split_bf16(v, hh, ll);
          Chi[cidx] = hh; Clo[cidx] = ll;
        } else {
          int tr = crows[moff + gm];
          atomicAdd(&C[(long)tr * ldc + gn], cw[moff + gm] * v);
        }
      }
    }
  }
}

// ---------------------------------------------------------------- index logits via MFMA (3-term split bf16)
// hi operands staged+swizzled in LDS (32 KB); lo operands loaded direct from global (L2-resident)
__global__ __launch_bounds__(256) void index_score_mfma(
    const u16* __restrict__ iqhi, const u16* __restrict__ iqlo,
    const u16* __restrict__ ikhi, const u16* __restrict__ iklo,
    const float* __restrict__ iww, int iws, float* __restrict__ ts)
{
  int s0 = blockIdx.x * 64, t0 = blockIdx.y * 64;
  int tid = threadIdx.x;
  if (s0 > t0 + 63) {
    for (int r = 0; r < 16; ++r) {
      int lin = r * 256 + tid;
      int i = lin >> 6, j = lin & 63;
      ts[(size_t)(t0 + i) * TT + s0 + j] = NEGF;
    }
    return;
  }
  __shared__ u16 Ah[64][128];
  __shared__ u16 Bh[64][128];

#pragma unroll
  for (int itr = 0; itr < 4; ++itr) {
    int it = tid + itr * 256;
    int r = it >> 4, c = it & 15;
    int cs = (c ^ (r & 7)) * 8;
    *(uint4*)&Bh[r][cs] = *(const uint4*)(ikhi + (size_t)(s0 + r) * 128 + c * 8);
  }

  int wid = tid >> 6, lane = tid & 63;
  int wr = wid >> 1, wc = wid & 1;
  int frow = lane & 15, kq = lane >> 4;

  f4v accts[2][2];
#pragma unroll
  for (int i = 0; i < 2; ++i)
#pragma unroll
    for (int j = 0; j < 2; ++j) accts[i][j] = (f4v){0.f, 0.f, 0.f, 0.f};

  for (int h = 0; h < 16; ++h) {
    __syncthreads();
    const u16* iqh_p = iqhi + (size_t)t0 * 2048 + h * 128;
#pragma unroll
    for (int itr = 0; itr < 4; ++itr) {
      int it = tid + itr * 256;
      int r = it >> 4, c = it & 15;
      int cs = (c ^ (r & 7)) * 8;
      *(uint4*)&Ah[r][cs] = *(const uint4*)(iqh_p + (size_t)r * 2048 + c * 8);
    }
    __syncthreads();
    f4v acch[2][2];
#pragma unroll
    for (int i = 0; i < 2; ++i)
#pragma unroll
      for (int j = 0; j < 2; ++j) acch[i][j] = (f4v){0.f, 0.f, 0.f, 0.f};
#pragma unroll
    for (int ks = 0; ks < 4; ++ks) {
      int col = (ks * 4 + kq) * 8;
      s8v ah[2], al[2], bh[2], bl[2];
#pragma unroll
      for (int i = 0; i < 2; ++i) {
        int rr = wr * 32 + i * 16 + frow;
        int cb = ((ks * 4 + kq) ^ (rr & 7)) * 8;
        ah[i] = *(const s8v*)&Ah[rr][cb];
        al[i] = *(const s8v*)(iqlo + (size_t)(t0 + rr) * 2048 + h * 128 + col);
      }
#pragma unroll
      for (int j = 0; j < 2; ++j) {
        int rr = wc * 32 + j * 16 + frow;
        int cb = ((ks * 4 + kq) ^ (rr & 7)) * 8;
        bh[j] = *(const s8v*)&Bh[rr][cb];
        bl[j] = *(const s8v*)(iklo + (size_t)(s0 + rr) * 128 + col);
      }
#pragma unroll
      for (int i = 0; i < 2; ++i)
#pragma unroll
        for (int j = 0; j < 2; ++j) {
          acch[i][j] = __builtin_amdgcn_mfma_f32_16x16x32_bf16(ah[i], bh[j], acch[i][j], 0, 0, 0);
          acch[i][j] = __builtin_amdgcn_mfma_f32_16x16x32_bf16(ah[i], bl[j], acch[i][j], 0, 0, 0);
          acch[i][j] = __builtin_amdgcn_mfma_f32_16x16x32_bf16(al[i], bh[j], acch[i][j], 0, 0, 0);
        }
    }
#pragma unroll
    for (int i = 0; i < 2; ++i) {
#pragma unroll
      for (int r = 0; r < 4; ++r) {
        int tl = wr * 32 + i * 16 + kq * 4 + r;
        float wv = iww[(size_t)(t0 + tl) * iws + h];
#pragma unroll
        for (int j = 0; j < 2; ++j)
          accts[i][j][r] += fmaxf(acch[i][j][r], 0.f) * wv;
      }
    }
  }
#pragma unroll
  for (int i = 0; i < 2; ++i) {
#pragma unroll
    for (int j = 0; j < 2; ++j) {
      int ssb = s0 + wc * 32 + j * 16 + frow;
#pragma unroll
      for (int r = 0; r < 4; ++r) {
        int tt = t0 + wr * 32 + i * 16 + kq * 4 + r;
        ts[(size_t)tt * TT + ssb] = (ssb <= tt) ? accts[i][j][r] : NEGF;
      }
    }
  }
}

// ---------------------------------------------------------------- exact top-256 per row via radix select
__global__ __launch_bounds__(256) void topk_kernel(
    const float* __restrict__ ts, int* __restrict__ sel_idx, int* __restrict__ sel_cnt)
{
  int t = blockIdx.x, tid = threadIdx.x;
  __shared__ unsigned keys[2048];
  __shared__ int hist[256];
  __shared__ int scan[256];
  __shared__ int sh_b, sh_r, sh_G;
  const float* row = ts + (size_t)t * TT;
  for (int i = tid; i < 2048; i += 256) {
    unsigned u = __float_as_uint(row[i]);
    keys[i] = (u & 0x80000000u) ? ~u : (u | 0x80000000u);
  }
  if (tid == 0) { sh_r = TOPKN; sh_G = 0; }
  unsigned prefix = 0, pmask = 0;
  __syncthreads();
  for (int lvl = 0; lvl < 4; ++lvl) {
    int sh = 24 - lvl * 8;
    hist[tid] = 0;
    __syncthreads();
    for (int i = tid; i < 2048; i += 256) {
      unsigned k = keys[i];
      if ((k & pmask) == prefix) atomicAdd(&hist[(k >> sh) & 255], 1);
    }
    __syncthreads();
    if (tid == 0) {
      int r = sh_r, G = sh_G;
      int b = 255;
      for (;; --b) {
        int c = hist[b];
        if (c >= r) break;
        r -= c; G += c;
      }
      sh_b = b; sh_r = r; sh_G = G;
    }
    __syncthreads();
    prefix |= ((unsigned)sh_b) << sh;
    pmask |= 0xFFu << sh;
    __syncthreads();
  }
  unsigned kth = prefix;
  int G = sh_G;
  int R = TOPKN - G;
  int base = tid * 8;
  int ceq = 0;
  for (int c = 0; c < 8; ++c) ceq += (keys[base + c] == kth);
  scan[tid] = ceq;
  __syncthreads();
  for (int off = 1; off < 256; off <<= 1) {
    int add = (tid >= off) ? scan[tid - off] : 0;
    __syncthreads();
    scan[tid] += add;
    __syncthreads();
  }
  int eqb = scan[tid] - ceq;
  unsigned flags = 0; int nsel = 0, eqrun = 0;
  for (int c = 0; c < 8; ++c) {
    int s = base + c; unsigned k = keys[s];
    bool sel = (k > kth) || ((k == kth) && (eqb + eqrun < R));
    eqrun += (k == kth);
    sel = sel && (s <= t);
    if (sel) { flags |= 1u << c; ++nsel; }
  }
  __syncthreads();
  scan[tid] = nsel;
  __syncthreads();
  for (int off = 1; off < 256; off <<= 1) {
    int add = (tid >= off) ? scan[tid - off] : 0;
    __syncthreads();
    scan[tid] += add;
    __syncthreads();
  }
  int wbase = scan[tid] - nsel;
  int k2 = 0;
  for (int c = 0; c < 8; ++c)
    if (flags & (1u << c)) { sel_idx[(size_t)t * TOPKN + wbase + k2] = base + c; ++k2; }
  if (tid == 255) sel_cnt[t] = scan[255];
}

// ---------------------------------------------------------------- attn core via MFMA, 512 threads / 8 waves
// pass1 k-split: waves 0-3 dims 0..287 -> S1, waves 4-7 dims 288..575 -> S2; softmax over (S1+S2)*SCALEF.
// pass2: wave w owns output dims [w*64, w*64+64).
#define SM_TILE 0
#define SM_QH   74752
#define SM_QL   93440
#define SM_S    112128
#define SM_S2   128768
#define SM_SIDX 145408
#define SM_INVD 146432
#define SM_TOT  146496
__global__ __launch_bounds__(512) void attn_mfma(
    const u16* __restrict__ qlfhi, const u16* __restrict__ qlflo,
    const float* __restrict__ q, int tbase,
    const u16* __restrict__ kvb,
    const int* __restrict__ sel_idx, const int* __restrict__ sel_cnt,
    u16* __restrict__ ctxhi, u16* __restrict__ ctxlo)
{
  extern __shared__ char smem[];
  u16* tA = (u16*)(smem + SM_TILE);      // [64][584]
  u16* tT = (u16*)(smem + SM_TILE);      // [512][72]
  u16* qh = (u16*)(smem + SM_QH);        // [16][584]
  u16* ql = (u16*)(smem + SM_QL);        // [16][584]
  float* S1 = (float*)(smem + SM_S);     // [16][260]
  float* S2 = (float*)(smem + SM_S2);    // [16][260]
  int* sidx = (int*)(smem + SM_SIDX);    // [256]
  float* invd = (float*)(smem + SM_INVD);// [16]

  int lt = blockIdx.x, tid = threadIdx.x;
  int t = tbase + lt;
  int lane = tid & 63, w = tid >> 6;
  int frow = lane & 15, kq = lane >> 4;
  int wk = w >> 2;        // k-half
  int wn = w & 3;         // key sub-block (pass1)
  int cnt = sel_cnt[t];

  if (tid < 256) sidx[tid] = (tid < cnt) ? sel_idx[(long)t * TOPKN + tid] : 0;
  for (int u = tid; u < 16 * 72; u += 512) {
    int h = u / 72, dg = u % 72; int d = dg * 8;
    if (d < 512) {
      uint4 vh = *(const uint4*)(qlfhi + (long)lt * 8192 + h * 512 + d);
      uint4 vl = *(const uint4*)(qlflo + (long)lt * 8192 + h * 512 + d);
      *(uint4*)(qh + h * 584 + d) = vh;
      *(uint4*)(ql + h * 584 + d) = vl;
    } else {
      const float* src = q + (long)t * QW + h * 192 + 128 + (d - 512);
      float4 a = *(const float4*)src;
      float4 b = *(const float4*)(src + 4);
      float pv[8] = {a.x, a.y, a.z, a.w, b.x, b.y, b.z, b.w};
      u16 hh[8], ll[8];
#pragma unroll
      for (int j = 0; j < 8; ++j) split_bf16(pv[j], hh[j], ll[j]);
#pragma unroll
      for (int j = 0; j < 8; ++j) { qh[h * 584 + d + j] = hh[j]; ql[h * 584 + d + j] = ll[j]; }
    }
  }
  __syncthreads();
  // ---- pass 1: scores (k-split across wave halves)
  for (int tile = 0; tile < 4; ++tile) {
#pragma unroll
    for (int it = 0; it < 9; ++it) {
      int u = tid + it * 512;
      int dg = u % 72, s = u / 72;
      int key = sidx[tile * 64 + s];
      uint4 v = *(const uint4*)(kvb + (long)key * 576 + dg * 8);
      *(uint4*)(tA + s * 584 + dg * 8) = v;
    }
    __syncthreads();
    f4v acc = (f4v){0.f, 0.f, 0.f, 0.f};
#pragma unroll
    for (int ki = 0; ki < 9; ++ki) {
      int ks = wk * 9 + ki;
      s8v a_h = *(const s8v*)(qh + frow * 584 + ks * 32 + kq * 8);
      s8v a_l = *(const s8v*)(ql + frow * 584 + ks * 32 + kq * 8);
      s8v b   = *(const s8v*)(tA + (wn * 16 + frow) * 584 + ks * 32 + kq * 8);
      acc = __builtin_amdgcn_mfma_f32_16x16x32_bf16(a_h, b, acc, 0, 0, 0);
      acc = __builtin_amdgcn_mfma_f32_16x16x32_bf16(a_l, b, acc, 0, 0, 0);
    }
    float* Sd = wk ? S2 : S1;
#pragma unroll
    for (int r = 0; r < 4; ++r)
      Sd[(kq * 4 + r) * 260 + tile * 64 + wn * 16 + frow] = acc[r];
    __syncthreads();
  }
  // ---- softmax over combined partials (16 heads x 32 lanes)
  {
    int h = tid >> 5, l = tid & 31;
    float m = -INFINITY;
    for (int i = l; i < 256; i += 32)
      if (i < cnt) m = fmaxf(m, (S1[h * 260 + i] + S2[h * 260 + i]) * SCALEF);
    for (int off2 = 16; off2; off2 >>= 1) m = fmaxf(m, __shfl_xor(m, off2, 32));
    float ssum = 0.f;
    for (int i = l; i < 256; i += 32) {
      float sv = (S1[h * 260 + i] + S2[h * 260 + i]) * SCALEF;
      float e = (i < cnt) ? expf(sv - m) : 0.f;
      S1[h * 260 + i] = e; ssum += e;
    }
    for (int off2 = 16; off2; off2 >>= 1) ssum += __shfl_xor(ssum, off2, 32);
    if (l == 0) invd[h] = 1.f / ssum;
  }
  __syncthreads();
  // ---- pass 2: ctx (P split 2-term); wave w owns dims [w*64, w*64+64)
  f4v cacc[4];
#pragma unroll
  for (int nt = 0; nt < 4; ++nt) cacc[nt] = (f4v){0.f, 0.f, 0.f, 0.f};
  for (int tile = 0; tile < 4; ++tile) {
#pragma unroll
    for (int it = 0; it < 8; ++it) {
      int u = tid + it * 512;
      int s = u & 63, dg = u >> 6;
      int key = sidx[tile * 64 + s];
      uint4 v = *(const uint4*)(kvb + (long)key * 576 + dg * 8);
      u16 tmp[8]; *(uint4*)tmp = v;
#pragma unroll
      for (int j = 0; j < 8; ++j) tT[(dg * 8 + j) * 72 + s] = tmp[j];
    }
    __syncthreads();
#pragma unroll
    for (int ks = 0; ks < 2; ++ks) {
      float4 p0 = *(const float4*)(S1 + frow * 260 + tile * 64 + ks * 32 + kq * 8);
      float4 p1 = *(const float4*)(S1 + frow * 260 + tile * 64 + ks * 32 + kq * 8 + 4);
      float pv[8] = {p0.x, p0.y, p0.z, p0.w, p1.x, p1.y, p1.z, p1.w};
      union { s8v v; u16 u[8]; } pah, pal;
#pragma unroll
      for (int j = 0; j < 8; ++j) split_bf16(pv[j], pah.u[j], pal.u[j]);
#pragma unroll
      for (int nt = 0; nt < 4; ++nt) {
        s8v b = *(const s8v*)(tT + (w * 64 + nt * 16 + frow) * 72 + ks * 32 + kq * 8);
        cacc[nt] = __builtin_amdgcn_mfma_f32_16x16x32_bf16(pah.v, b, cacc[nt], 0, 0, 0);
        cacc[nt] = __builtin_amdgcn_mfma_f32_16x16x32_bf16(pal.v, b, cacc[nt], 0, 0, 0);
      }
    }
    __syncthreads();
  }
#pragma unroll
  for (int nt = 0; nt < 4; ++nt) {
    int dim = w * 64 + nt * 16 + frow;
#pragma unroll
    for (int r = 0; r < 4; ++r) {
      int head = kq * 4 + r;
      float v = cacc[nt][r] * invd[head];
      u16 hh, ll; split_bf16(v, hh, ll);
      long ob = (long)lt * 8192 + head * 512 + dim;
      ctxhi[ob] = hh; ctxlo[ob] = ll;
    }
  }
}

// ---------------------------------------------------------------- fused silu*mul -> bf16 hi
__global__ void silu_cvt(const float* __restrict__ u, const float* __restrict__ v,
                         u16* __restrict__ outhi, long n)
{
  long i = ((long)blockIdx.x * 256 + threadIdx.x) * 4;
  if (i >= n) return;
  float4 a = *(const float4*)(u + i);
  float4 b = *(const float4*)(v + i);
  ushort4 h;
  h.x = rnd_bf16(a.x / (1.f + expf(-a.x)) * b.x);
  h.y = rnd_bf16(a.y / (1.f + expf(-a.y)) * b.y);
  h.z = rnd_bf16(a.z / (1.f + expf(-a.z)) * b.z);
  h.w = rnd_bf16(a.w / (1.f + expf(-a.w)) * b.w);
  *(ushort4*)(outhi + i) = h;
}

__global__ void zero_counts(int* cnt, int* cursor)
{ int i = threadIdx.x; if (i < 8) { cnt[i] = 0; cursor[i] = 0; } }

__global__ void gate_pick(const float* __restrict__ glog,
                          int* __restrict__ e01, float* __restrict__ w01, int* __restrict__ cnt)
{
  int t = blockIdx.x * 256 + threadIdx.x;
  if (t >= TT) return;
  float lg[8];
#pragma unroll
  for (int i = 0; i < 8; ++i) lg[i] = glog[(long)t * 8 + i];
  float m = lg[0];
#pragma unroll
  for (int i = 1; i < 8; ++i) m = fmaxf(m, lg[i]);
  float pe[8];
#pragma unroll
  for (int i = 0; i < 8; ++i) pe[i] = expf(lg[i] - m);
  int i0 = 0;
  for (int i = 1; i < 8; ++i) if (pe[i] > pe[i0]) i0 = i;
  int i1 = (i0 == 0) ? 1 : 0;
  for (int i = 0; i < 8; ++i) if (i != i0 && pe[i] > pe[i1]) i1 = i;
  float w0 = pe[i0], w1v = pe[i1];
  float invs = 1.f / (w0 + w1v);
  e01[2 * t] = i0; e01[2 * t + 1] = i1;
  w01[2 * t] = w0 * invs; w01[2 * t + 1] = w1v * invs;
  atomicAdd(&cnt[i0], 1); atomicAdd(&cnt[i1], 1);
}

__global__ void offsets_kernel(const int* cnt, int* offs)
{
  if (threadIdx.x == 0) {
    int a = 0;
    for (int e = 0; e < 8; ++e) { offs[e] = a; a += cnt[e]; }
    offs[8] = a;
  }
}

__global__ void build_list(const int* __restrict__ e01, const float* __restrict__ w01,
                           const int* __restrict__ offs, int* __restrict__ cursor,
                           int* __restrict__ list_tok, float* __restrict__ wlist)
{
  int t = blockIdx.x * 256 + threadIdx.x;
  if (t >= TT) return;
  for (int k = 0; k < 2; ++k) {
    int e = e01[2 * t + k];
    int p2 = atomicAdd(&cursor[e], 1);
    int g = offs[e] + p2;
    list_tok[g] = t;
    wlist[g] = w01[2 * t + k] * 2.5f;
  }
}

// ================================================================ host
extern "C" void kernel_launch(void* const* d_in, const int* in_sizes, int n_in,
                              void* d_out, int out_size, void* d_ws, size_t ws_size,
                              hipStream_t stream)
{
  (void)in_sizes; (void)n_in; (void)out_size; (void)ws_size;
  const int*   positions = (const int*)d_in[0];
  const float* hidden    = (const float*)d_in[1];
  const float* w_in      = (const float*)d_in[2];
  const float* w_post    = (const float*)d_in[3];
  const float* W_qkv_a   = (const float*)d_in[4];
  const float* w_qa      = (const float*)d_in[5];
  const float* w_kva     = (const float*)d_in[6];
  const float* W_qb      = (const float*)d_in[7];
  const float* W_ik      = (const float*)d_in[8];
  const float* ik_ln_w   = (const float*)d_in[9];
  const float* ik_ln_b   = (const float*)d_in[10];
  const float* W_iw      = (const float*)d_in[11];
  const float* W_iqb     = (const float*)d_in[12];
  const float* W_UKT     = (const float*)d_in[13];
  const float* W_UV      = (const float*)d_in[14];
  const float* W_o       = (const float*)d_in[15];
  const float* W_gate    = (const float*)d_in[16];
  const float* We1       = (const float*)d_in[17];
  const float* We3       = (const float*)d_in[18];
  const float* We2       = (const float*)d_in[19];
  const float* Ws1       = (const float*)d_in[20];
  const float* Ws3       = (const float*)d_in[21];
  const float* Ws2       = (const float*)d_in[22];

  float* outp  = (float*)d_out;
  float* resid = outp + (size_t)TT * DD;

  float* ws = (float*)d_ws;
  size_t o = 0;
  auto take = [&](size_t n) { float* p = ws + o; o += n; return p; };
  float* kvbF  = take(589824);    // kvb bf16 [2048][576] | head of bv
  float* reg1  = take(4325376);   // bqkvx f32 [2048][1488] | qnhi+qnlo | tail of bv
  float* qcF   = take(1572864);   // q_c hi+lo
  float* bikF  = take(262144);    // ikhi+iklo bf16
  float* biw   = take(32768);     // glog [2048][8]
  float* bq    = take(6291456);   // qfull part1 | bu+uhi
  float* biq   = take(4194304);   // qfull part2 | us+vs
  float* bts   = take(4194304);   // ts | chunk qlfhi+qlflo | bo | ushi
  float* wshiF = take(4194304);   // weight-hi | iqhi+iqlo | chunk ctxhi+ctxlo
  float* wsloF = take(2097152);   // weight-lo | wukt/wuv hi+lo
  u16*   hhi   = (u16*)take(2097152);  // h hi | bahi | h2 hi
  u16*   hlo   = (u16*)take(2097152);  // h lo | balo | h2 lo
  int*   bsel  = (int*)take(524288);
  int*   bselc = (int*)take(2048);
  int*   be01  = (int*)take(4096);
  float* bw01  = take(4096);
  int*   bcnt  = (int*)take(16);
  int*   boff  = (int*)take(16);
  int*   bcur  = (int*)take(16);
  int*   blist = (int*)take(4096);
  float* bwlist= take(4096);

  // phased aliases
  u16*   kvb   = (u16*)kvbF;
  float* bqkvx = reg1;                          // [2048][1488]
  u16*   qnhi  = (u16*)reg1;
  u16*   qnlo  = qnhi + 4194304;
  u16*   qchi  = (u16*)qcF;
  u16*   qclo  = qchi + 1572864;
  u16*   ikhi  = (u16*)bikF;
  u16*   iklo  = ikhi + 262144;
  float* qfull = bq;                            // [2048][5120] spans bq+biq (exact)
  u16*   iqhi  = (u16*)wshiF;
  u16*   iqlo  = iqhi + 4194304;
  u16*   qlfhi = (u16*)bts;                     // chunk [512][8192]
  u16*   qlflo = (u16*)(bts + 2097152);
  u16*   ctxhi = (u16*)wshiF;                   // chunk [512][8192]
  u16*   ctxlo = (u16*)(wshiF + 2097152);
  u16*   bahi  = hhi;                           // battn hi [2048][2048] (h dead)
  u16*   balo  = hlo;
  float* bo    = bts;
  u16*   ushi  = (u16*)bts;
  float* glog  = biw;
  u16*   wshi  = (u16*)wshiF;
  u16*   wslo  = (u16*)wsloF;
  u16*   wukthi = (u16*)wsloF;                  // 16x512x128 hi
  u16*   wuktlo = wukthi + 1048576;
  u16*   wuvhi  = wukthi + 2097152;             // 16x128x512 hi
  u16*   wuvlo  = wukthi + 3145728;
  float* bu    = bq;
  u16*   uhi   = (u16*)(bq + 4194304);
  float* us    = biq;
  float* vs    = biq + 2097152;
  float* bv    = kvbF;                          // spans kvbF+reg1

  const int* NOI = nullptr; const float* NOF = nullptr;
  u16* NOU = nullptr;
  float* NOFP = nullptr;

  // 1. h = rms_norm(hidden, w_in) -> hi/lo ; pre-zero split-K target bqkvx
  hipMemsetAsync(bqkvx, 0, (size_t)TT * QKVW * 4, stream);
  rms_kernel<<<TT, 256, 0, stream>>>(hidden, DD, DD, w_in, NOFP, 0, hhi, hlo, DD);
  // 2. merged qkv+ik+iw projection (N=1488, iw scale folded), split-K 2
  cvt_wT<<<dim3(1344 / 32, DD / 32, 1), 256, 0, stream>>>(W_qkv_a, wshi, wslo, DD, 1344);
  cvt_wT<<<dim3(DII / 32, DD / 32, 1), 256, 0, stream>>>(W_ik, wshi + (long)1344 * DD, wslo + (long)1344 * DD, DD, DII);
  cvt_wT_small<<<(HII * DD + 255) / 256, 256, 0, stream>>>(W_iw, wshi + (long)1472 * DD, wslo + (long)1472 * DD, DD, HII, 0.25f);
  gemm_bx2<3, 0, 2><<<dim3(12, 16, 2), 256, 0, stream>>>(
      hhi, hlo, DD, 0, wshi, wslo, 0, bqkvx, NOU, NOU, QKVW, 0,
      TT, QKVW, DD, NOI, NOI, NOI, NOI, NOF);
  // 3. q_c -> hi/lo ; kv_c -> kvb ; k_pe -> kvb ; index_k -> ik hi/lo
  rms_kernel<<<TT, 256, 0, stream>>>(bqkvx, QKVW, QLL, w_qa, NOFP, 0, qchi, qclo, QLL);
  rms_kernel<<<TT, 256, 0, stream>>>(bqkvx + QLL, QKVW, KVLL, w_kva, NOFP, 0, kvb, NOU, 576);
  rope_kpe<<<TT, 64, 0, stream>>>(bqkvx, positions, kvb);
  ln_rope_ik<<<TT, 128, 0, stream>>>(bqkvx + 1344, QKVW, ik_ln_w, ik_ln_b, positions, ikhi, iklo);
  // 4. merged q+iq projection (N=5120) -> qfull
  cvt_wT<<<dim3(3072 / 32, QLL / 32, 1), 256, 0, stream>>>(W_qb, wshi, wslo, QLL, 3072);
  cvt_wT<<<dim3(2048 / 32, QLL / 32, 1), 256, 0, stream>>>(W_iqb, wshi + (long)3072 * QLL, wslo + (long)3072 * QLL, QLL, 2048);
  gemm_bx2<3, 0><<<dim3(40, 16, 1), 256, 0, stream>>>(
      qchi, qclo, QLL, 0, wshi, wslo, 0, qfull, NOU, NOU, QW, 0,
      TT, QW, QLL, NOI, NOI, NOI, NOI, NOF);
  // 5. iq rope+cvt ; index logits (iw from bqkvx col 1472) ; top-256
  rope_iq_cvt<<<TT, 256, 0, stream>>>(qfull, positions, iqhi, iqlo);
  index_score_mfma<<<dim3(32, 32, 1), 256, 0, stream>>>(iqhi, iqlo, ikhi, iklo, bqkvx + 1472, QKVW, bts);
  topk_kernel<<<TT, 256, 0, stream>>>(bts, bsel, bselc);
  // 6. rope q_pe in place ; q_nope -> qn hi/lo
  rope_qpe<<<TT, 512, 0, stream>>>(qfull, positions);
  cvt_qnope<<<TT, 256, 0, stream>>>(qfull, qnhi, qnlo);
  // 7. attention weights ; 4 chunks of 512 tokens
  cvt_wT<<<dim3(KVLL / 32, DNN / 32, NH), 256, 0, stream>>>(W_UKT, wukthi, wuktlo, DNN, KVLL);
  cvt_wT<<<dim3(DVV / 32, KVLL / 32, NH), 256, 0, stream>>>(W_UV, wuvhi, wuvlo, KVLL, DVV);
  for (int c = 0; c < TT / CHK; ++c) {
    int base = c * CHK;
    gemm_bx2<3, 1><<<dim3(4, CHK / 128, NH), 256, 0, stream>>>(
        qnhi + (long)base * 2048, qnlo + (long)base * 2048, 2048, 128,
        wukthi, wuktlo, (long)KVLL * DNN,
        nullptr, qlfhi, qlflo, NH * KVLL, KVLL,
        CHK, KVLL, DNN, NOI, NOI, NOI, NOI, NOF);
    attn_mfma<<<CHK, 512, SM_TOT, stream>>>(qlfhi, qlflo, qfull, base, kvb, bsel, bselc, ctxhi, ctxlo);
    gemm_bx2<3, 1><<<dim3(1, CHK / 128, NH), 256, 0, stream>>>(
        ctxhi, ctxlo, NH * KVLL, KVLL,
        wuvhi, wuvlo, (long)DVV * KVLL,
        nullptr, bahi + (long)base * DD, balo + (long)base * DD, DD, DVV,
        CHK, DVV, KVLL, NOI, NOI, NOI, NOI, NOF);
  }
  // 8. o = attn @ W_o -> bo (split-K 2, pre-zeroed) ; residual+post-norm
  hipMemsetAsync(bo, 0, (size_t)TT * DD * 4, stream);
  cvt_wT<<<dim3(DD / 32, DD / 32, 1), 256, 0, stream>>>(W_o, wshi, wslo, DD, DD);
  gemm_bx2<3, 0, 2><<<dim3(16, 16, 2), 256, 0, stream>>>(
      bahi, balo, DD, 0, wshi, wslo, 0, bo, NOU, NOU, DD, 0,
      TT, DD, DD, NOI, NOI, NOI, NOI, NOF);
  res_rms<<<TT, 256, 0, stream>>>(bo, hidden, w_post, resid, hhi, hlo);
  // 9. gate via GEMM (split-K 2) + pick ; compaction
  zero_counts<<<1, 64, 0, stream>>>(bcnt, bcur);
  hipMemsetAsync(glog, 0, (size_t)TT * NEE * 4, stream);
  cvt_wT_small<<<(NEE * DD + 255) / 256, 256, 0, stream>>>(W_gate, wshi, wslo, DD, NEE, 1.0f);
  gemm_bx2<3, 0, 2><<<dim3(1, 16, 2), 256, 0, stream>>>(
      hhi, hlo, DD, 0, wshi, wslo, 0, glog, NOU, NOU, NEE, 0,
      TT, NEE, DD, NOI, NOI, NOI, NOI, NOF);
  gate_pick<<<TT / 256, 256, 0, stream>>>(glog, be01, bw01, bcnt);
  offsets_kernel<<<1, 64, 0, stream>>>(bcnt, boff);
  build_list<<<TT / 256, 256, 0, stream>>>(be01, bw01, boff, bcur, blist, bwlist);
  // 10. shared expert -> outp (plain store; precedes routed atomics); Ws1/Ws3 split-K 2
  hipMemsetAsync(us, 0, (size_t)2 * TT * MII * 4, stream);   // zeroes us and vs (contiguous)
  cvt_wT<<<dim3(MII / 32, DD / 32, 1), 256, 0, stream>>>(Ws1, wshi, NOU, DD, MII);
  gemm_bx2<1, 0, 2><<<dim3(8, 16, 2), 256, 0, stream>>>(
      hhi, NOU, DD, 0, wshi, NOU, 0, us, NOU, NOU, MII, 0,
      TT, MII, DD, NOI, NOI, NOI, NOI, NOF);
  cvt_wT<<<dim3(MII / 32, DD / 32, 1), 256, 0, stream>>>(Ws3, wshi, NOU, DD, MII);
  gemm_bx2<1, 0, 2><<<dim3(8, 16, 2), 256, 0, stream>>>(
      hhi, NOU, DD, 0, wshi, NOU, 0, vs, NOU, NOU, MII, 0,
      TT, MII, DD, NOI, NOI, NOI, NOI, NOF);
  silu_cvt<<<(TT * MII) / 1024, 256, 0, stream>>>(us, vs, ushi, (long)TT * MII);
  cvt_wT<<<dim3(DD / 32, MII / 32, 1), 256, 0, stream>>>(Ws2, wshi, NOU, MII, DD);
  gemm_bx2<1, 0><<<dim3(16, 16, 1), 256, 0, stream>>>(
      ushi, NOU, MII, 0, wshi, NOU, 0, outp, NOU, NOU, DD, 0,
      TT, DD, MII, NOI, NOI, NOI, NOI, NOF);
  // 11. routed experts (half-batches of 4), atomic scatter into outp
  for (int hf = 0; hf < 2; ++hf) {
    const float* w1p = We1 + (size_t)hf * 4 * DD * MII;
    cvt_wT<<<dim3(MII / 32, DD / 32, 4), 256, 0, stream>>>(w1p, wshi, NOU, DD, MII);
    gemm_bx2<1, 0><<<dim3(8, 16, 4), 256, 0, stream>>>(
        hhi, NOU, DD, 0, wshi, NOU, (long)DD * MII, bu, NOU, NOU, MII, 0,
        0, MII, DD, blist, boff + 4 * hf, bcnt + 4 * hf, NOI, NOF);
  }
  for (int hf = 0; hf < 2; ++hf) {
    const float* w3p = We3 + (size_t)hf * 4 * DD * MII;
    cvt_wT<<<dim3(MII / 32, DD / 32, 4), 256, 0, stream>>>(w3p, wshi, NOU, DD, MII);
    gemm_bx2<1, 0><<<dim3(8, 16, 4), 256, 0, stream>>>(
        hhi, NOU, DD, 0, wshi, NOU, (long)DD * MII, bv, NOU, NOU, MII, 0,
        0, MII, DD, blist, boff + 4 * hf, bcnt + 4 * hf, NOI, NOF);
  }
  silu_cvt<<<(2 * TT * MII) / 1024, 256, 0, stream>>>(bu, bv, uhi, (long)2 * TT * MII);
  for (int hf = 0; hf < 2; ++hf) {
    const float* w2p = We2 + (size_t)hf * 4 * MII * DD;
    cvt_wT<<<dim3(DD / 32, MII / 32, 4), 256, 0, stream>>>(w2p, wshi, NOU, MII, DD);
    gemm_bx2<1, 2><<<dim3(16, 16, 4), 256, 0, stream>>>(
        uhi, NOU, MII, 0, wshi, NOU, (long)MII * DD, outp, NOU, NOU, DD, 0,
        0, DD, MII, NOI, boff + 4 * hf, bcnt + 4 * hf, blist, bwlist);
  }
}

// Round 13
// 1469.776 us; speedup vs baseline: 1.0174x; 1.0174x over previous
//
#include <hip/hip_runtime.h>
#include <hip/hip_bf16.h>
#include <math.h>

#define TT 2048
#define DD 2048
#define NH 16
#define DNN 128
#define DRR 64
#define DVV 128
#define QLL 768
#define KVLL 512
#define HII 16
#define DII 128
#define TOPKN 256
#define NEE 8
#define MII 1024
#define QKVW 1488            // 1344 qkv + 128 ik + 16 iw
#define QW 5120              // 3072 q + 2048 iq
#define EPSF 1e-6f
#define NEGF (-1e30f)
#define SCALEF 0.07216878364870323f
#define IQSCALE 0.08838834764831845f
#define LOG1E4 9.210340371976184f
#define CHK 512              // attention token chunk

typedef unsigned short u16;
typedef __attribute__((ext_vector_type(8))) short s8v;
typedef __attribute__((ext_vector_type(4))) float f4v;

__device__ inline void split_bf16(float x, u16& h, u16& l) {
  __hip_bfloat16 bh_ = __float2bfloat16(x);
  float hf = __bfloat162float(bh_);
  __hip_bfloat16 bl_ = __float2bfloat16(x - hf);
  h = *(u16*)&bh_; l = *(u16*)&bl_;
}
__device__ inline u16 rnd_bf16(float x) {
  __hip_bfloat16 b = __float2bfloat16(x);
  return *(u16*)&b;
}
__device__ inline float b2f(u16 h) { return __uint_as_float(((unsigned)h) << 16); }

// ---------------------------------------------------------------- RMS norm (f32 and/or bf16 hi(+lo) outputs)
__global__ __launch_bounds__(256) void rms_kernel(
    const float* __restrict__ src, int sstride, int width,
    const float* __restrict__ w,
    float* __restrict__ dstf, int dfstride,
    u16* __restrict__ dsthi, u16* __restrict__ dstlo, int dhstride)
{
  int t = blockIdx.x, tid = threadIdx.x;
  const float* x = src + (size_t)t * sstride;
  float ss = 0.f;
  for (int i = tid; i < width; i += 256) { float v = x[i]; ss += v * v; }
  for (int off = 32; off; off >>= 1) ss += __shfl_down(ss, off, 64);
  __shared__ float red[4];
  __shared__ float scale_sh;
  if ((tid & 63) == 0) red[tid >> 6] = ss;
  __syncthreads();
  if (tid == 0) {
    float tot = red[0] + red[1] + red[2] + red[3];
    scale_sh = rsqrtf(tot / (float)width + EPSF);
  }
  __syncthreads();
  float sc2 = scale_sh;
  for (int i = tid; i < width; i += 256) {
    float y = x[i] * sc2 * w[i];
    if (dstf) dstf[(size_t)t * dfstride + i] = y;
    if (dsthi) {
      if (dstlo) {
        u16 h, l; split_bf16(y, h, l);
        dsthi[(size_t)t * dhstride + i] = h;
        dstlo[(size_t)t * dhstride + i] = l;
      } else {
        dsthi[(size_t)t * dhstride + i] = rnd_bf16(y);
      }
    }
  }
}

// ---------------------------------------------------------------- residual + RMS + bf16 hi/lo
__global__ __launch_bounds__(256) void res_rms(
    const float* __restrict__ o, const float* __restrict__ hid,
    const float* __restrict__ w,
    float* __restrict__ resid, u16* __restrict__ dhi, u16* __restrict__ dlo)
{
  int t = blockIdx.x, tid = threadIdx.x;
  long base = (long)t * DD;
  float xv[8];
  float ss = 0.f;
#pragma unroll
  for (int j = 0; j < 8; ++j) {
    int i = j * 256 + tid;
    float v = o[base + i] + hid[base + i];
    xv[j] = v; resid[base + i] = v; ss += v * v;
  }
  for (int off = 32; off; off >>= 1) ss += __shfl_down(ss, off, 64);
  __shared__ float red[4];
  __shared__ float scale_sh;
  if ((tid & 63) == 0) red[tid >> 6] = ss;
  __syncthreads();
  if (tid == 0) scale_sh = rsqrtf((red[0] + red[1] + red[2] + red[3]) / (float)DD + EPSF);
  __syncthreads();
  float sc2 = scale_sh;
#pragma unroll
  for (int j = 0; j < 8; ++j) {
    int i = j * 256 + tid;
    float y = xv[j] * sc2 * w[i];
    u16 h, l; split_bf16(y, h, l);
    dhi[base + i] = h; dlo[base + i] = l;
  }
}

// ---------------------------------------------------------------- LayerNorm + RoPE for index_k -> bf16 hi/lo (strided src)
__global__ __launch_bounds__(128) void ln_rope_ik(
    const float* __restrict__ src, int sstride,
    const float* __restrict__ w, const float* __restrict__ b,
    const int* __restrict__ pos, u16* __restrict__ dhi, u16* __restrict__ dlo)
{
  int t = blockIdx.x, tid = threadIdx.x;
  __shared__ float rowv[128];
  __shared__ float red[2];
  float v = src[(size_t)t * sstride + tid];
  float s = v;
  for (int off = 32; off; off >>= 1) s += __shfl_down(s, off, 64);
  if ((tid & 63) == 0) red[tid >> 6] = s;
  __syncthreads();
  float mu = (red[0] + red[1]) * (1.f / 128.f);
  __syncthreads();
  float dlt = v - mu;
  float s2 = dlt * dlt;
  for (int off = 32; off; off >>= 1) s2 += __shfl_down(s2, off, 64);
  if ((tid & 63) == 0) red[tid >> 6] = s2;
  __syncthreads();
  float var = (red[0] + red[1]) * (1.f / 128.f);
  float yv = dlt * rsqrtf(var + EPSF) * w[tid] + b[tid];
  rowv[tid] = yv;
  __syncthreads();
  if (tid < 64) {
    float x1 = rowv[tid], x2 = rowv[tid + 64];
    float p = (float)pos[t];
    float invf = expf(-(2.f * tid / 128.f) * LOG1E4);
    float f = p * invf;
    float cf = cosf(f), sf = sinf(f);
    float y1 = x1 * cf - x2 * sf;
    float y2 = x2 * cf + x1 * sf;
    u16 h1, l1, h2, l2;
    split_bf16(y1, h1, l1); split_bf16(y2, h2, l2);
    long base = (size_t)t * DII + tid;
    dhi[base] = h1; dlo[base] = l1;
    dhi[base + 64] = h2; dlo[base + 64] = l2;
  }
}

// k_pe rope -> kvb bf16 (cols 512..576); qkvx row stride QKVW
__global__ void rope_kpe(const float* __restrict__ qkv, const int* __restrict__ pos, u16* __restrict__ kvb)
{
  int t = blockIdx.x, tid = threadIdx.x;
  if (tid < 32) {
    const float* x = qkv + (size_t)t * QKVW + QLL + KVLL;
    float x1 = x[tid], x2 = x[tid + 32];
    float p = (float)pos[t];
    float invf = expf(-(2.f * tid / 64.f) * LOG1E4);
    float f = p * invf, cf = cosf(f), sf = sinf(f);
    kvb[(long)t * 576 + 512 + tid]      = rnd_bf16(x1 * cf - x2 * sf);
    kvb[(long)t * 576 + 512 + tid + 32] = rnd_bf16(x2 * cf + x1 * sf);
  }
}

// q_pe rope IN-PLACE on qfull (row stride QW, head stride 192, pe at +128)
__global__ void rope_qpe(float* __restrict__ q, const int* __restrict__ pos)
{
  int t = blockIdx.x, tid = threadIdx.x;  // 512 threads
  int h = tid >> 5, j = tid & 31;
  float* x = q + (size_t)t * QW + h * 192 + 128;
  float x1 = x[j], x2 = x[j + 32];
  float p = (float)pos[t];
  float invf = expf(-(2.f * j / 64.f) * LOG1E4);
  float f = p * invf, cf = cosf(f), sf = sinf(f);
  x[j]      = x1 * cf - x2 * sf;
  x[j + 32] = x2 * cf + x1 * sf;
}

// index_q rope + scale + split to bf16 hi/lo; iq at qfull cols 3072+, stride QW
__global__ __launch_bounds__(256) void rope_iq_cvt(
    const float* __restrict__ q, const int* __restrict__ pos,
    u16* __restrict__ dhi, u16* __restrict__ dlo)
{
  int t = blockIdx.x, tid = threadIdx.x;
  float p = (float)pos[t];
#pragma unroll
  for (int r = 0; r < 4; ++r) {
    int e = r * 256 + tid;
    int h = e >> 6, j = e & 63;
    long src = (long)t * QW + 3072 + h * 128 + j;
    long dst = (long)t * 2048 + h * 128 + j;
    float x1 = q[src], x2 = q[src + 64];
    float invf = expf(-(2.f * j / 128.f) * LOG1E4);
    float f = p * invf, cf = cosf(f), sf = sinf(f);
    float y1 = (x1 * cf - x2 * sf) * IQSCALE;
    float y2 = (x2 * cf + x1 * sf) * IQSCALE;
    u16 h1, l1, h2, l2;
    split_bf16(y1, h1, l1); split_bf16(y2, h2, l2);
    dhi[dst] = h1; dlo[dst] = l1;
    dhi[dst + 64] = h2; dlo[dst + 64] = l2;
  }
}

// q_nope [T][H][128] from qfull [T][QW] -> bf16 hi/lo
__global__ __launch_bounds__(256) void cvt_qnope(
    const float* __restrict__ q, u16* __restrict__ hi, u16* __restrict__ lo)
{
  int t = blockIdx.x;
  int e = threadIdx.x * 8;
  int h = e >> 7, d = e & 127;
  const float* src = q + (long)t * QW + h * 192 + d;
  float4 a = *(const float4*)src;
  float4 b = *(const float4*)(src + 4);
  ushort4 h0, l0, h1, l1;
  split_bf16(a.x, h0.x, l0.x); split_bf16(a.y, h0.y, l0.y);
  split_bf16(a.z, h0.z, l0.z); split_bf16(a.w, h0.w, l0.w);
  split_bf16(b.x, h1.x, l1.x); split_bf16(b.y, h1.y, l1.y);
  split_bf16(b.z, h1.z, l1.z); split_bf16(b.w, h1.w, l1.w);
  long ob = (long)t * 2048 + e;
  *(ushort4*)(hi + ob) = h0; *(ushort4*)(hi + ob + 4) = h1;
  *(ushort4*)(lo + ob) = l0; *(ushort4*)(lo + ob + 4) = l1;
}

// ---------------------------------------------------------------- weights [Z][K][N] f32 -> [Z][N][K] bf16 hi(+lo)
__global__ __launch_bounds__(256) void cvt_wT(
    const float* __restrict__ W, u16* __restrict__ hiT, u16* __restrict__ loT, int K, int N)
{
  int z = blockIdx.z;
  const float* in = W + (long)z * K * N;
  u16* ho = hiT + (long)z * K * N;
  u16* lo2 = loT ? loT + (long)z * K * N : nullptr;
  int k0 = blockIdx.y * 32, n0 = blockIdx.x * 32;
  __shared__ float tile[32][33];
  int r = threadIdx.x >> 3, c4 = (threadIdx.x & 7) * 4;
  float4 v = *(const float4*)(in + (long)(k0 + r) * N + n0 + c4);
  tile[r][c4] = v.x; tile[r][c4 + 1] = v.y; tile[r][c4 + 2] = v.z; tile[r][c4 + 3] = v.w;
  __syncthreads();
  float a0 = tile[c4 + 0][r], a1 = tile[c4 + 1][r], a2 = tile[c4 + 2][r], a3 = tile[c4 + 3][r];
  ushort4 h, l;
  split_bf16(a0, h.x, l.x);
  split_bf16(a1, h.y, l.y);
  split_bf16(a2, h.z, l.z);
  split_bf16(a3, h.w, l.w);
  long ob = (long)(n0 + r) * K + k0 + c4;
  *(ushort4*)(ho + ob) = h;
  if (lo2) *(ushort4*)(lo2 + ob) = l;
}

// small-N weight transpose with scale
__global__ void cvt_wT_small(const float* __restrict__ W, u16* __restrict__ hiT, u16* __restrict__ loT,
                             int K, int N, float scale)
{
  int i = blockIdx.x * 256 + threadIdx.x;
  if (i >= K * N) return;
  int n = i / K, k = i - n * K;
  float v = W[(long)k * N + n] * scale;
  u16 h, l; split_bf16(v, h, l);
  hiT[i] = h; loT[i] = l;
}

// ---------------------------------------------------------------- split-bf16 MFMA GEMM; BT pre-transposed [N][K].
// TERMS: 3 = AhBh+AhBl+AlBh (≈f32) ; 1 = AhBh
// OUTMODE: 0 = f32 ; 1 = split hi/lo ; 2 = atomicAdd scatter C[crows[row]] += cw[row]*v
// KS: split-K factor (OUTMODE 0 only); KS>1 uses atomicAdd into pre-zeroed C.
template<int TERMS, int OUTMODE, int KS = 1>
__global__ __launch_bounds__(256) void gemm_bx2(
    const u16* __restrict__ Ahi, const u16* __restrict__ Alo, int lda, long astride,
    const u16* __restrict__ BThi, const u16* __restrict__ BTlo, long bstride,
    float* __restrict__ C, u16* __restrict__ Chi, u16* __restrict__ Clo, int ldc, long cstride,
    int M, int N, int K,
    const int* __restrict__ rowlist, const int* __restrict__ offs, const int* __restrict__ cnts,
    const int* __restrict__ crows, const float* __restrict__ cw)
{
  int zz = blockIdx.z;
  int ksp = (KS > 1) ? (zz % KS) : 0;
  int z = (KS > 1) ? (zz / KS) : zz;
  Ahi += (long)z * astride;
  BThi += (long)z * bstride;
  if (TERMS == 3) { Alo += (long)z * astride; BTlo += (long)z * bstride; }
  if (OUTMODE == 1) { Chi += (long)z * cstride; Clo += (long)z * cstride; }
  else { C += (long)z * cstride; }
  int moff = 0, Mloc = M;
  if (offs) { moff = offs[z]; Mloc = cnts[z]; }
  int m0 = blockIdx.y * 128;
  if (m0 >= Mloc) return;
  int n0 = blockIdx.x * 128;
  int tid = threadIdx.x;

  __shared__ u16 Ah[128][40];
  __shared__ u16 Bh[128][40];
  __shared__ u16 Al[TERMS == 3 ? 128 : 1][40];
  __shared__ u16 Bl[TERMS == 3 ? 128 : 1][40];

  int r0 = tid >> 2, c0 = (tid & 3) * 8;
  int r1 = 64 + r0, c1 = c0;

  long aoff0 = -1, aoff1 = -1;
  {
    int g0 = moff + m0 + r0;
    int g1 = moff + m0 + r1;
    if (m0 + r0 < Mloc) aoff0 = (long)(rowlist ? rowlist[g0] : g0) * lda;
    if (m0 + r1 < Mloc) aoff1 = (long)(rowlist ? rowlist[g1] : g1) * lda;
  }
  long boff0 = (n0 + r0 < N) ? (long)(n0 + r0) * K : -1;
  long boff1 = (n0 + r1 < N) ? (long)(n0 + r1) * K : -1;

  f4v acc[4][4];
#pragma unroll
  for (int i = 0; i < 4; ++i)
#pragma unroll
    for (int j = 0; j < 4; ++j) acc[i][j] = (f4v){0.f, 0.f, 0.f, 0.f};

  int wid = tid >> 6, lane = tid & 63;
  int wr = wid >> 1, wc = wid & 1;
  int frow = lane & 15, koct = (lane >> 4) * 8;

  int kbeg = (KS > 1) ? (K / KS) * ksp : 0;
  int kend = (KS > 1) ? kbeg + K / KS : K;
  for (int kt = kbeg; kt < kend; kt += 32) {
    uint4 zzv = make_uint4(0, 0, 0, 0);
    uint4 ah0 = zzv, ah1 = zzv, bh0 = zzv, bh1 = zzv;
    uint4 al0 = zzv, al1 = zzv, bl0 = zzv, bl1 = zzv;
    if (aoff0 >= 0) ah0 = *(const uint4*)(Ahi + aoff0 + kt + c0);
    if (aoff1 >= 0) ah1 = *(const uint4*)(Ahi + aoff1 + kt + c1);
    if (boff0 >= 0) bh0 = *(const uint4*)(BThi + boff0 + kt + c0);
    if (boff1 >= 0) bh1 = *(const uint4*)(BThi + boff1 + kt + c1);
    if (TERMS == 3) {
      if (aoff0 >= 0) al0 = *(const uint4*)(Alo + aoff0 + kt + c0);
      if (aoff1 >= 0) al1 = *(const uint4*)(Alo + aoff1 + kt + c1);
      if (boff0 >= 0) bl0 = *(const uint4*)(BTlo + boff0 + kt + c0);
      if (boff1 >= 0) bl1 = *(const uint4*)(BTlo + boff1 + kt + c1);
    }
    __syncthreads();
    *(uint4*)&Ah[r0][c0] = ah0;
    *(uint4*)&Ah[r1][c1] = ah1;
    *(uint4*)&Bh[r0][c0] = bh0;
    *(uint4*)&Bh[r1][c1] = bh1;
    if (TERMS == 3) {
      *(uint4*)&Al[r0][c0] = al0;
      *(uint4*)&Al[r1][c1] = al1;
      *(uint4*)&Bl[r0][c0] = bl0;
      *(uint4*)&Bl[r1][c1] = bl1;
    }
    __syncthreads();

    s8v af_h[4], af_l[4];
#pragma unroll
    for (int i = 0; i < 4; ++i) {
      af_h[i] = *(const s8v*)&Ah[wr * 64 + i * 16 + frow][koct];
      if (TERMS == 3) af_l[i] = *(const s8v*)&Al[wr * 64 + i * 16 + frow][koct];
    }
#pragma unroll
    for (int j = 0; j < 4; ++j) {
      s8v bf_h = *(const s8v*)&Bh[wc * 64 + j * 16 + frow][koct];
      s8v bf_l;
      if (TERMS == 3) bf_l = *(const s8v*)&Bl[wc * 64 + j * 16 + frow][koct];
#pragma unroll
      for (int i = 0; i < 4; ++i) {
        acc[i][j] = __builtin_amdgcn_mfma_f32_16x16x32_bf16(af_h[i], bf_h, acc[i][j], 0, 0, 0);
        if (TERMS == 3) {
          acc[i][j] = __builtin_amdgcn_mfma_f32_16x16x32_bf16(af_h[i], bf_l, acc[i][j], 0, 0, 0);
          acc[i][j] = __builtin_amdgcn_mfma_f32_16x16x32_bf16(af_l[i], bf_h, acc[i][j], 0, 0, 0);
        }
      }
    }
  }

  // C/D layout: col = lane&15, row = (lane>>4)*4 + reg
#pragma unroll
  for (int i = 0; i < 4; ++i) {
    int gmb = m0 + wr * 64 + i * 16 + (lane >> 4) * 4;
#pragma unroll
    for (int j = 0; j < 4; ++j) {
      int gn = n0 + wc * 64 + j * 16 + (lane & 15);
      if (gn >= N) continue;
#pragma unroll
      for (int r = 0; r < 4; ++r) {
        int gm = gmb + r;
        if (gm >= Mloc) continue;
        float v = acc[i][j][r];
        long cidx = (long)(moff + gm) * ldc + gn;
        if (OUTMODE == 0) {
          if (KS > 1) atomicAdd(&C[cidx], v);
          else C[cidx] = v;
        } else if (OUTMODE == 1) {
          u16 hh, ll; split_bf16(v, hh, ll);
          Chi[cidx] = hh; Clo[cidx] = ll;
        } else {
          int tr = crows[moff + gm];
          atomicAdd(&C[(long)tr * ldc + gn], cw[moff + gm] * v);
        }
      }
    }
  }
}

// ---------------------------------------------------------------- index logits via MFMA (3-term split bf16) — round-11 staged version
__global__ __launch_bounds__(256) void index_score_mfma(
    const u16* __restrict__ iqhi, const u16* __restrict__ iqlo,
    const u16* __restrict__ ikhi, const u16* __restrict__ iklo,
    const float* __restrict__ iww, int iws, float* __restrict__ ts)
{
  int s0 = blockIdx.x * 64, t0 = blockIdx.y * 64;
  int tid = threadIdx.x;
  if (s0 > t0 + 63) {
    for (int r = 0; r < 16; ++r) {
      int lin = r * 256 + tid;
      int i = lin >> 6, j = lin & 63;
      ts[(size_t)(t0 + i) * TT + s0 + j] = NEGF;
    }
    return;
  }
  __shared__ u16 Ah[64][128];
  __shared__ u16 Al[64][128];
  __shared__ u16 Bh[64][128];
  __shared__ u16 Bl[64][128];

  for (int it = tid; it < 1024; it += 256) {
    int r = it >> 4, c = it & 15;
    int cs = (c ^ (r & 7)) * 8;
    *(uint4*)&Bh[r][cs] = *(const uint4*)(ikhi + (size_t)(s0 + r) * 128 + c * 8);
    *(uint4*)&Bl[r][cs] = *(const uint4*)(iklo + (size_t)(s0 + r) * 128 + c * 8);
  }

  int wid = tid >> 6, lane = tid & 63;
  int wr = wid >> 1, wc = wid & 1;
  int frow = lane & 15, kq = lane >> 4;

  f4v accts[2][2];
#pragma unroll
  for (int i = 0; i < 2; ++i)
#pragma unroll
    for (int j = 0; j < 2; ++j) accts[i][j] = (f4v){0.f, 0.f, 0.f, 0.f};

  for (int h = 0; h < 16; ++h) {
    __syncthreads();
    const u16* iqh_p = iqhi + (size_t)t0 * 2048 + h * 128;
    const u16* iql_p = iqlo + (size_t)t0 * 2048 + h * 128;
    for (int it = tid; it < 1024; it += 256) {
      int r = it >> 4, c = it & 15;
      int cs = (c ^ (r & 7)) * 8;
      *(uint4*)&Ah[r][cs] = *(const uint4*)(iqh_p + (size_t)r * 2048 + c * 8);
      *(uint4*)&Al[r][cs] = *(const uint4*)(iql_p + (size_t)r * 2048 + c * 8);
    }
    __syncthreads();
    f4v acch[2][2];
#pragma unroll
    for (int i = 0; i < 2; ++i)
#pragma unroll
      for (int j = 0; j < 2; ++j) acch[i][j] = (f4v){0.f, 0.f, 0.f, 0.f};
#pragma unroll
    for (int ks = 0; ks < 4; ++ks) {
      s8v ah[2], al[2], bh[2], bl[2];
#pragma unroll
      for (int i = 0; i < 2; ++i) {
        int rr = wr * 32 + i * 16 + frow;
        int cb = ((ks * 4 + kq) ^ (rr & 7)) * 8;
        ah[i] = *(const s8v*)&Ah[rr][cb];
        al[i] = *(const s8v*)&Al[rr][cb];
      }
#pragma unroll
      for (int j = 0; j < 2; ++j) {
        int rr = wc * 32 + j * 16 + frow;
        int cb = ((ks * 4 + kq) ^ (rr & 7)) * 8;
        bh[j] = *(const s8v*)&Bh[rr][cb];
        bl[j] = *(const s8v*)&Bl[rr][cb];
      }
#pragma unroll
      for (int i = 0; i < 2; ++i)
#pragma unroll
        for (int j = 0; j < 2; ++j) {
          acch[i][j] = __builtin_amdgcn_mfma_f32_16x16x32_bf16(ah[i], bh[j], acch[i][j], 0, 0, 0);
          acch[i][j] = __builtin_amdgcn_mfma_f32_16x16x32_bf16(ah[i], bl[j], acch[i][j], 0, 0, 0);
          acch[i][j] = __builtin_amdgcn_mfma_f32_16x16x32_bf16(al[i], bh[j], acch[i][j], 0, 0, 0);
        }
    }
#pragma unroll
    for (int i = 0; i < 2; ++i) {
#pragma unroll
      for (int r = 0; r < 4; ++r) {
        int tl = wr * 32 + i * 16 + kq * 4 + r;
        float wv = iww[(size_t)(t0 + tl) * iws + h];
#pragma unroll
        for (int j = 0; j < 2; ++j)
          accts[i][j][r] += fmaxf(acch[i][j][r], 0.f) * wv;
      }
    }
  }
#pragma unroll
  for (int i = 0; i < 2; ++i) {
#pragma unroll
    for (int j = 0; j < 2; ++j) {
      int ssb = s0 + wc * 32 + j * 16 + frow;
#pragma unroll
      for (int r = 0; r < 4; ++r) {
        int tt = t0 + wr * 32 + i * 16 + kq * 4 + r;
        ts[(size_t)tt * TT + ssb] = (ssb <= tt) ? accts[i][j][r] : NEGF;
      }
    }
  }
}

// ---------------------------------------------------------------- exact top-256 per row via radix select
__global__ __launch_bounds__(256) void topk_kernel(
    const float* __restrict__ ts, int* __restrict__ sel_idx, int* __restrict__ sel_cnt)
{
  int t = blockIdx.x, tid = threadIdx.x;
  __shared__ unsigned keys[2048];
  __shared__ int hist[256];
  __shared__ int scan[256];
  __shared__ int sh_b, sh_r, sh_G;
  const float* row = ts + (size_t)t * TT;
  for (int i = tid; i < 2048; i += 256) {
    unsigned u = __float_as_uint(row[i]);
    keys[i] = (u & 0x80000000u) ? ~u : (u | 0x80000000u);
  }
  if (tid == 0) { sh_r = TOPKN; sh_G = 0; }
  unsigned prefix = 0, pmask = 0;
  __syncthreads();
  for (int lvl = 0; lvl < 4; ++lvl) {
    int sh = 24 - lvl * 8;
    hist[tid] = 0;
    __syncthreads();
    for (int i = tid; i < 2048; i += 256) {
      unsigned k = keys[i];
      if ((k & pmask) == prefix) atomicAdd(&hist[(k >> sh) & 255], 1);
    }
    __syncthreads();
    if (tid == 0) {
      int r = sh_r, G = sh_G;
      int b = 255;
      for (;; --b) {
        int c = hist[b];
        if (c >= r) break;
        r -= c; G += c;
      }
      sh_b = b; sh_r = r; sh_G = G;
    }
    __syncthreads();
    prefix |= ((unsigned)sh_b) << sh;
    pmask |= 0xFFu << sh;
    __syncthreads();
  }
  unsigned kth = prefix;
  int G = sh_G;
  int R = TOPKN - G;
  int base = tid * 8;
  int ceq = 0;
  for (int c = 0; c < 8; ++c) ceq += (keys[base + c] == kth);
  scan[tid] = ceq;
  __syncthreads();
  for (int off = 1; off < 256; off <<= 1) {
    int add = (tid >= off) ? scan[tid - off] : 0;
    __syncthreads();
    scan[tid] += add;
    __syncthreads();
  }
  int eqb = scan[tid] - ceq;
  unsigned flags = 0; int nsel = 0, eqrun = 0;
  for (int c = 0; c < 8; ++c) {
    int s = base + c; unsigned k = keys[s];
    bool sel = (k > kth) || ((k == kth) && (eqb + eqrun < R));
    eqrun += (k == kth);
    sel = sel && (s <= t);
    if (sel) { flags |= 1u << c; ++nsel; }
  }
  __syncthreads();
  scan[tid] = nsel;
  __syncthreads();
  for (int off = 1; off < 256; off <<= 1) {
    int add = (tid >= off) ? scan[tid - off] : 0;
    __syncthreads();
    scan[tid] += add;
    __syncthreads();
  }
  int wbase = scan[tid] - nsel;
  int k2 = 0;
  for (int c = 0; c < 8; ++c)
    if (flags & (1u << c)) { sel_idx[(size_t)t * TOPKN + wbase + k2] = base + c; ++k2; }
  if (tid == 255) sel_cnt[t] = scan[255];
}

// ---------------------------------------------------------------- attn core via MFMA, 512 threads / 8 waves
#define SM_TILE 0
#define SM_QH   74752
#define SM_QL   93440
#define SM_S    112128
#define SM_S2   128768
#define SM_SIDX 145408
#define SM_INVD 146432
#define SM_TOT  146496
__global__ __launch_bounds__(512) void attn_mfma(
    const u16* __restrict__ qlfhi, const u16* __restrict__ qlflo,
    const float* __restrict__ q, int tbase,
    const u16* __restrict__ kvb,
    const int* __restrict__ sel_idx, const int* __restrict__ sel_cnt,
    u16* __restrict__ ctxhi, u16* __restrict__ ctxlo)
{
  extern __shared__ char smem[];
  u16* tA = (u16*)(smem + SM_TILE);      // [64][584]
  u16* tT = (u16*)(smem + SM_TILE);      // [512][72]
  u16* qh = (u16*)(smem + SM_QH);        // [16][584]
  u16* ql = (u16*)(smem + SM_QL);        // [16][584]
  float* S1 = (float*)(smem + SM_S);     // [16][260]
  float* S2 = (float*)(smem + SM_S2);    // [16][260]
  int* sidx = (int*)(smem + SM_SIDX);    // [256]
  float* invd = (float*)(smem + SM_INVD);// [16]

  int lt = blockIdx.x, tid = threadIdx.x;
  int t = tbase + lt;
  int lane = tid & 63, w = tid >> 6;
  int frow = lane & 15, kq = lane >> 4;
  int wk = w >> 2;        // k-half
  int wn = w & 3;         // key sub-block (pass1)
  int cnt = sel_cnt[t];

  if (tid < 256) sidx[tid] = (tid < cnt) ? sel_idx[(long)t * TOPKN + tid] : 0;
  for (int u = tid; u < 16 * 72; u += 512) {
    int h = u / 72, dg = u % 72; int d = dg * 8;
    if (d < 512) {
      uint4 vh = *(const uint4*)(qlfhi + (long)lt * 8192 + h * 512 + d);
      uint4 vl = *(const uint4*)(qlflo + (long)lt * 8192 + h * 512 + d);
      *(uint4*)(qh + h * 584 + d) = vh;
      *(uint4*)(ql + h * 584 + d) = vl;
    } else {
      const float* src = q + (long)t * QW + h * 192 + 128 + (d - 512);
      float4 a = *(const float4*)src;
      float4 b = *(const float4*)(src + 4);
      float pv[8] = {a.x, a.y, a.z, a.w, b.x, b.y, b.z, b.w};
      u16 hh[8], ll[8];
#pragma unroll
      for (int j = 0; j < 8; ++j) split_bf16(pv[j], hh[j], ll[j]);
#pragma unroll
      for (int j = 0; j < 8; ++j) { qh[h * 584 + d + j] = hh[j]; ql[h * 584 + d + j] = ll[j]; }
    }
  }
  __syncthreads();
  // ---- pass 1: scores (k-split across wave halves)
  for (int tile = 0; tile < 4; ++tile) {
#pragma unroll
    for (int it = 0; it < 9; ++it) {
      int u = tid + it * 512;
      int dg = u % 72, s = u / 72;
      int key = sidx[tile * 64 + s];
      uint4 v = *(const uint4*)(kvb + (long)key * 576 + dg * 8);
      *(uint4*)(tA + s * 584 + dg * 8) = v;
    }
    __syncthreads();
    f4v acc = (f4v){0.f, 0.f, 0.f, 0.f};
#pragma unroll
    for (int ki = 0; ki < 9; ++ki) {
      int ks = wk * 9 + ki;
      s8v a_h = *(const s8v*)(qh + frow * 584 + ks * 32 + kq * 8);
      s8v a_l = *(const s8v*)(ql + frow * 584 + ks * 32 + kq * 8);
      s8v b   = *(const s8v*)(tA + (wn * 16 + frow) * 584 + ks * 32 + kq * 8);
      acc = __builtin_amdgcn_mfma_f32_16x16x32_bf16(a_h, b, acc, 0, 0, 0);
      acc = __builtin_amdgcn_mfma_f32_16x16x32_bf16(a_l, b, acc, 0, 0, 0);
    }
    float* Sd = wk ? S2 : S1;
#pragma unroll
    for (int r = 0; r < 4; ++r)
      Sd[(kq * 4 + r) * 260 + tile * 64 + wn * 16 + frow] = acc[r];
    __syncthreads();
  }
  // ---- softmax over combined partials (16 heads x 32 lanes)
  {
    int h = tid >> 5, l = tid & 31;
    float m = -INFINITY;
    for (int i = l; i < 256; i += 32)
      if (i < cnt) m = fmaxf(m, (S1[h * 260 + i] + S2[h * 260 + i]) * SCALEF);
    for (int off2 = 16; off2; off2 >>= 1) m = fmaxf(m, __shfl_xor(m, off2, 32));
    float ssum = 0.f;
    for (int i = l; i < 256; i += 32) {
      float sv = (S1[h * 260 + i] + S2[h * 260 + i]) * SCALEF;
      float e = (i < cnt) ? expf(sv - m) : 0.f;
      S1[h * 260 + i] = e; ssum += e;
    }
    for (int off2 = 16; off2; off2 >>= 1) ssum += __shfl_xor(ssum, off2, 32);
    if (l == 0) invd[h] = 1.f / ssum;
  }
  __syncthreads();
  // ---- pass 2: ctx (P split 2-term); wave w owns dims [w*64, w*64+64)
  f4v cacc[4];
#pragma unroll
  for (int nt = 0; nt < 4; ++nt) cacc[nt] = (f4v){0.f, 0.f, 0.f, 0.f};
  for (int tile = 0; tile < 4; ++tile) {
#pragma unroll
    for (int it = 0; it < 8; ++it) {
      int u = tid + it * 512;
      int s = u & 63, dg = u >> 6;
      int key = sidx[tile * 64 + s];
      uint4 v = *(const uint4*)(kvb + (long)key * 576 + dg * 8);
      u16 tmp[8]; *(uint4*)tmp = v;
#pragma unroll
      for (int j = 0; j < 8; ++j) tT[(dg * 8 + j) * 72 + s] = tmp[j];
    }
    __syncthreads();
#pragma unroll
    for (int ks = 0; ks < 2; ++ks) {
      float4 p0 = *(const float4*)(S1 + frow * 260 + tile * 64 + ks * 32 + kq * 8);
      float4 p1 = *(const float4*)(S1 + frow * 260 + tile * 64 + ks * 32 + kq * 8 + 4);
      float pv[8] = {p0.x, p0.y, p0.z, p0.w, p1.x, p1.y, p1.z, p1.w};
      union { s8v v; u16 u[8]; } pah, pal;
#pragma unroll
      for (int j = 0; j < 8; ++j) split_bf16(pv[j], pah.u[j], pal.u[j]);
#pragma unroll
      for (int nt = 0; nt < 4; ++nt) {
        s8v b = *(const s8v*)(tT + (w * 64 + nt * 16 + frow) * 72 + ks * 32 + kq * 8);
        cacc[nt] = __builtin_amdgcn_mfma_f32_16x16x32_bf16(pah.v, b, cacc[nt], 0, 0, 0);
        cacc[nt] = __builtin_amdgcn_mfma_f32_16x16x32_bf16(pal.v, b, cacc[nt], 0, 0, 0);
      }
    }
    __syncthreads();
  }
#pragma unroll
  for (int nt = 0; nt < 4; ++nt) {
    int dim = w * 64 + nt * 16 + frow;
#pragma unroll
    for (int r = 0; r < 4; ++r) {
      int head = kq * 4 + r;
      float v = cacc[nt][r] * invd[head];
      u16 hh, ll; split_bf16(v, hh, ll);
      long ob = (long)lt * 8192 + head * 512 + dim;
      ctxhi[ob] = hh; ctxlo[ob] = ll;
    }
  }
}

// ---------------------------------------------------------------- fused silu*mul -> bf16 hi
__global__ void silu_cvt(const float* __restrict__ u, const float* __restrict__ v,
                         u16* __restrict__ outhi, long n)
{
  long i = ((long)blockIdx.x * 256 + threadIdx.x) * 4;
  if (i >= n) return;
  float4 a = *(const float4*)(u + i);
  float4 b = *(const float4*)(v + i);
  ushort4 h;
  h.x = rnd_bf16(a.x / (1.f + expf(-a.x)) * b.x);
  h.y = rnd_bf16(a.y / (1.f + expf(-a.y)) * b.y);
  h.z = rnd_bf16(a.z / (1.f + expf(-a.z)) * b.z);
  h.w = rnd_bf16(a.w / (1.f + expf(-a.w)) * b.w);
  *(ushort4*)(outhi + i) = h;
}

__global__ void zero_counts(int* cnt, int* cursor)
{ int i = threadIdx.x; if (i < 8) { cnt[i] = 0; cursor[i] = 0; } }

__global__ void gate_pick(const float* __restrict__ glog,
                          int* __restrict__ e01, float* __restrict__ w01, int* __restrict__ cnt)
{
  int t = blockIdx.x * 256 + threadIdx.x;
  if (t >= TT) return;
  float lg[8];
#pragma unroll
  for (int i = 0; i < 8; ++i) lg[i] = glog[(long)t * 8 + i];
  float m = lg[0];
#pragma unroll
  for (int i = 1; i < 8; ++i) m = fmaxf(m, lg[i]);
  float pe[8];
#pragma unroll
  for (int i = 0; i < 8; ++i) pe[i] = expf(lg[i] - m);
  int i0 = 0;
  for (int i = 1; i < 8; ++i) if (pe[i] > pe[i0]) i0 = i;
  int i1 = (i0 == 0) ? 1 : 0;
  for (int i = 0; i < 8; ++i) if (i != i0 && pe[i] > pe[i1]) i1 = i;
  float w0 = pe[i0], w1v = pe[i1];
  float invs = 1.f / (w0 + w1v);
  e01[2 * t] = i0; e01[2 * t + 1] = i1;
  w01[2 * t] = w0 * invs; w01[2 * t + 1] = w1v * invs;
  atomicAdd(&cnt[i0], 1); atomicAdd(&cnt[i1], 1);
}

__global__ void offsets_kernel(const int* cnt, int* offs)
{
  if (threadIdx.x == 0) {
    int a = 0;
    for (int e = 0; e < 8; ++e) { offs[e] = a; a += cnt[e]; }
    offs[8] = a;
  }
}

__global__ void build_list(const int* __restrict__ e01, const float* __restrict__ w01,
                           const int* __restrict__ offs, int* __restrict__ cursor,
                           int* __restrict__ list_tok, float* __restrict__ wlist)
{
  int t = blockIdx.x * 256 + threadIdx.x;
  if (t >= TT) return;
  for (int k = 0; k < 2; ++k) {
    int e = e01[2 * t + k];
    int p2 = atomicAdd(&cursor[e], 1);
    int g = offs[e] + p2;
    list_tok[g] = t;
    wlist[g] = w01[2 * t + k] * 2.5f;
  }
}

// ================================================================ host
extern "C" void kernel_launch(void* const* d_in, const int* in_sizes, int n_in,
                              void* d_out, int out_size, void* d_ws, size_t ws_size,
                              hipStream_t stream)
{
  (void)in_sizes; (void)n_in; (void)out_size; (void)ws_size;
  const int*   positions = (const int*)d_in[0];
  const float* hidden    = (const float*)d_in[1];
  const float* w_in      = (const float*)d_in[2];
  const float* w_post    = (const float*)d_in[3];
  const float* W_qkv_a   = (const float*)d_in[4];
  const float* w_qa      = (const float*)d_in[5];
  const float* w_kva     = (const float*)d_in[6];
  const float* W_qb      = (const float*)d_in[7];
  const float* W_ik      = (const float*)d_in[8];
  const float* ik_ln_w   = (const float*)d_in[9];
  const float* ik_ln_b   = (const float*)d_in[10];
  const float* W_iw      = (const float*)d_in[11];
  const float* W_iqb     = (const float*)d_in[12];
  const float* W_UKT     = (const float*)d_in[13];
  const float* W_UV      = (const float*)d_in[14];
  const float* W_o       = (const float*)d_in[15];
  const float* W_gate    = (const float*)d_in[16];
  const float* We1       = (const float*)d_in[17];
  const float* We3       = (const float*)d_in[18];
  const float* We2       = (const float*)d_in[19];
  const float* Ws1       = (const float*)d_in[20];
  const float* Ws3       = (const float*)d_in[21];
  const float* Ws2       = (const float*)d_in[22];

  float* outp  = (float*)d_out;
  float* resid = outp + (size_t)TT * DD;

  float* ws = (float*)d_ws;
  size_t o = 0;
  auto take = [&](size_t n) { float* p = ws + o; o += n; return p; };
  float* kvbF  = take(589824);    // kvb bf16 [2048][576] | head of bv
  float* reg1  = take(4325376);   // bqkvx f32 [2048][1488] | qnhi+qnlo | tail of bv
  float* qcF   = take(1572864);   // q_c hi+lo
  float* bikF  = take(262144);    // ikhi+iklo bf16
  float* biw   = take(32768);     // glog [2048][8]
  float* bq    = take(6291456);   // qfull part1 | bu+uhi
  float* biq   = take(4194304);   // qfull part2 | us+vs
  float* bts   = take(4194304);   // ts | chunk qlfhi+qlflo | bo | ushi
  float* wshiF = take(4194304);   // weight-hi | iqhi+iqlo | chunk ctxhi+ctxlo
  float* wsloF = take(2097152);   // weight-lo | wukt/wuv hi+lo
  u16*   hhi   = (u16*)take(2097152);  // h hi | bahi | h2 hi
  u16*   hlo   = (u16*)take(2097152);  // h lo | balo | h2 lo
  int*   bsel  = (int*)take(524288);
  int*   bselc = (int*)take(2048);
  int*   be01  = (int*)take(4096);
  float* bw01  = take(4096);
  int*   bcnt  = (int*)take(16);
  int*   boff  = (int*)take(16);
  int*   bcur  = (int*)take(16);
  int*   blist = (int*)take(4096);
  float* bwlist= take(4096);

  // phased aliases
  u16*   kvb   = (u16*)kvbF;
  float* bqkvx = reg1;                          // [2048][1488]
  u16*   qnhi  = (u16*)reg1;
  u16*   qnlo  = qnhi + 4194304;
  u16*   qchi  = (u16*)qcF;
  u16*   qclo  = qchi + 1572864;
  u16*   ikhi  = (u16*)bikF;
  u16*   iklo  = ikhi + 262144;
  float* qfull = bq;                            // [2048][5120] spans bq+biq (exact)
  u16*   iqhi  = (u16*)wshiF;
  u16*   iqlo  = iqhi + 4194304;
  u16*   qlfhi = (u16*)bts;                     // chunk [512][8192]
  u16*   qlflo = (u16*)(bts + 2097152);
  u16*   ctxhi = (u16*)wshiF;                   // chunk [512][8192]
  u16*   ctxlo = (u16*)(wshiF + 2097152);
  u16*   bahi  = hhi;                           // battn hi [2048][2048] (h dead)
  u16*   balo  = hlo;
  float* bo    = bts;
  u16*   ushi  = (u16*)bts;
  float* glog  = biw;
  u16*   wshi  = (u16*)wshiF;
  u16*   wslo  = (u16*)wsloF;
  u16*   wukthi = (u16*)wsloF;                  // 16x512x128 hi
  u16*   wuktlo = wukthi + 1048576;
  u16*   wuvhi  = wukthi + 2097152;             // 16x128x512 hi
  u16*   wuvlo  = wukthi + 3145728;
  float* bu    = bq;
  u16*   uhi   = (u16*)(bq + 4194304);
  float* us    = biq;
  float* vs    = biq + 2097152;
  float* bv    = kvbF;                          // spans kvbF+reg1

  const int* NOI = nullptr; const float* NOF = nullptr;
  u16* NOU = nullptr;
  float* NOFP = nullptr;

  // 1. h = rms_norm(hidden, w_in) -> hi/lo ; pre-zero split-K target bqkvx
  hipMemsetAsync(bqkvx, 0, (size_t)TT * QKVW * 4, stream);
  rms_kernel<<<TT, 256, 0, stream>>>(hidden, DD, DD, w_in, NOFP, 0, hhi, hlo, DD);
  // 2. merged qkv+ik+iw projection (N=1488, iw scale folded), split-K 2
  cvt_wT<<<dim3(1344 / 32, DD / 32, 1), 256, 0, stream>>>(W_qkv_a, wshi, wslo, DD, 1344);
  cvt_wT<<<dim3(DII / 32, DD / 32, 1), 256, 0, stream>>>(W_ik, wshi + (long)1344 * DD, wslo + (long)1344 * DD, DD, DII);
  cvt_wT_small<<<(HII * DD + 255) / 256, 256, 0, stream>>>(W_iw, wshi + (long)1472 * DD, wslo + (long)1472 * DD, DD, HII, 0.25f);
  gemm_bx2<3, 0, 2><<<dim3(12, 16, 2), 256, 0, stream>>>(
      hhi, hlo, DD, 0, wshi, wslo, 0, bqkvx, NOU, NOU, QKVW, 0,
      TT, QKVW, DD, NOI, NOI, NOI, NOI, NOF);
  // 3. q_c -> hi/lo ; kv_c -> kvb ; k_pe -> kvb ; index_k -> ik hi/lo
  rms_kernel<<<TT, 256, 0, stream>>>(bqkvx, QKVW, QLL, w_qa, NOFP, 0, qchi, qclo, QLL);
  rms_kernel<<<TT, 256, 0, stream>>>(bqkvx + QLL, QKVW, KVLL, w_kva, NOFP, 0, kvb, NOU, 576);
  rope_kpe<<<TT, 64, 0, stream>>>(bqkvx, positions, kvb);
  ln_rope_ik<<<TT, 128, 0, stream>>>(bqkvx + 1344, QKVW, ik_ln_w, ik_ln_b, positions, ikhi, iklo);
  // 4. merged q+iq projection (N=5120) -> qfull
  cvt_wT<<<dim3(3072 / 32, QLL / 32, 1), 256, 0, stream>>>(W_qb, wshi, wslo, QLL, 3072);
  cvt_wT<<<dim3(2048 / 32, QLL / 32, 1), 256, 0, stream>>>(W_iqb, wshi + (long)3072 * QLL, wslo + (long)3072 * QLL, QLL, 2048);
  gemm_bx2<3, 0><<<dim3(40, 16, 1), 256, 0, stream>>>(
      qchi, qclo, QLL, 0, wshi, wslo, 0, qfull, NOU, NOU, QW, 0,
      TT, QW, QLL, NOI, NOI, NOI, NOI, NOF);
  // 5. iq rope+cvt ; index logits (iw from bqkvx col 1472) ; top-256
  rope_iq_cvt<<<TT, 256, 0, stream>>>(qfull, positions, iqhi, iqlo);
  index_score_mfma<<<dim3(32, 32, 1), 256, 0, stream>>>(iqhi, iqlo, ikhi, iklo, bqkvx + 1472, QKVW, bts);
  topk_kernel<<<TT, 256, 0, stream>>>(bts, bsel, bselc);
  // 6. rope q_pe in place ; q_nope -> qn hi/lo
  rope_qpe<<<TT, 512, 0, stream>>>(qfull, positions);
  cvt_qnope<<<TT, 256, 0, stream>>>(qfull, qnhi, qnlo);
  // 7. attention weights ; 4 chunks of 512 tokens
  cvt_wT<<<dim3(KVLL / 32, DNN / 32, NH), 256, 0, stream>>>(W_UKT, wukthi, wuktlo, DNN, KVLL);
  cvt_wT<<<dim3(DVV / 32, KVLL / 32, NH), 256, 0, stream>>>(W_UV, wuvhi, wuvlo, KVLL, DVV);
  for (int c = 0; c < TT / CHK; ++c) {
    int base = c * CHK;
    gemm_bx2<3, 1><<<dim3(4, CHK / 128, NH), 256, 0, stream>>>(
        qnhi + (long)base * 2048, qnlo + (long)base * 2048, 2048, 128,
        wukthi, wuktlo, (long)KVLL * DNN,
        nullptr, qlfhi, qlflo, NH * KVLL, KVLL,
        CHK, KVLL, DNN, NOI, NOI, NOI, NOI, NOF);
    attn_mfma<<<CHK, 512, SM_TOT, stream>>>(qlfhi, qlflo, qfull, base, kvb, bsel, bselc, ctxhi, ctxlo);
    gemm_bx2<3, 1><<<dim3(1, CHK / 128, NH), 256, 0, stream>>>(
        ctxhi, ctxlo, NH * KVLL, KVLL,
        wuvhi, wuvlo, (long)DVV * KVLL,
        nullptr, bahi + (long)base * DD, balo + (long)base * DD, DD, DVV,
        CHK, DVV, KVLL, NOI, NOI, NOI, NOI, NOF);
  }
  // 8. o = attn @ W_o -> bo (split-K 2, pre-zeroed) ; residual+post-norm
  hipMemsetAsync(bo, 0, (size_t)TT * DD * 4, stream);
  cvt_wT<<<dim3(DD / 32, DD / 32, 1), 256, 0, stream>>>(W_o, wshi, wslo, DD, DD);
  gemm_bx2<3, 0, 2><<<dim3(16, 16, 2), 256, 0, stream>>>(
      bahi, balo, DD, 0, wshi, wslo, 0, bo, NOU, NOU, DD, 0,
      TT, DD, DD, NOI, NOI, NOI, NOI, NOF);
  res_rms<<<TT, 256, 0, stream>>>(bo, hidden, w_post, resid, hhi, hlo);
  // 9. gate via GEMM (split-K 2) + pick ; compaction
  zero_counts<<<1, 64, 0, stream>>>(bcnt, bcur);
  hipMemsetAsync(glog, 0, (size_t)TT * NEE * 4, stream);
  cvt_wT_small<<<(NEE * DD + 255) / 256, 256, 0, stream>>>(W_gate, wshi, wslo, DD, NEE, 1.0f);
  gemm_bx2<3, 0, 2><<<dim3(1, 16, 2), 256, 0, stream>>>(
      hhi, hlo, DD, 0, wshi, wslo, 0, glog, NOU, NOU, NEE, 0,
      TT, NEE, DD, NOI, NOI, NOI, NOI, NOF);
  gate_pick<<<TT / 256, 256, 0, stream>>>(glog, be01, bw01, bcnt);
  offsets_kernel<<<1, 64, 0, stream>>>(bcnt, boff);
  build_list<<<TT / 256, 256, 0, stream>>>(be01, bw01, boff, bcur, blist, bwlist);
  // 10. shared expert -> outp (plain store; precedes routed atomics); Ws1/Ws3 split-K 2
  hipMemsetAsync(us, 0, (size_t)2 * TT * MII * 4, stream);   // zeroes us and vs (contiguous)
  cvt_wT<<<dim3(MII / 32, DD / 32, 1), 256, 0, stream>>>(Ws1, wshi, NOU, DD, MII);
  gemm_bx2<1, 0, 2><<<dim3(8, 16, 2), 256, 0, stream>>>(
      hhi, NOU, DD, 0, wshi, NOU, 0, us, NOU, NOU, MII, 0,
      TT, MII, DD, NOI, NOI, NOI, NOI, NOF);
  cvt_wT<<<dim3(MII / 32, DD / 32, 1), 256, 0, stream>>>(Ws3, wshi, NOU, DD, MII);
  gemm_bx2<1, 0, 2><<<dim3(8, 16, 2), 256, 0, stream>>>(
      hhi, NOU, DD, 0, wshi, NOU, 0, vs, NOU, NOU, MII, 0,
      TT, MII, DD, NOI, NOI, NOI, NOI, NOF);
  silu_cvt<<<(TT * MII) / 1024, 256, 0, stream>>>(us, vs, ushi, (long)TT * MII);
  cvt_wT<<<dim3(DD / 32, MII / 32, 1), 256, 0, stream>>>(Ws2, wshi, NOU, MII, DD);
  gemm_bx2<1, 0><<<dim3(16, 16, 1), 256, 0, stream>>>(
      ushi, NOU, MII, 0, wshi, NOU, 0, outp, NOU, NOU, DD, 0,
      TT, DD, MII, NOI, NOI, NOI, NOI, NOF);
  // 11. routed experts (half-batches of 4), u/v GEMMs split-K 2 (pre-zeroed), atomic scatter into outp
  hipMemsetAsync(bu, 0, (size_t)2 * TT * MII * 4, stream);
  hipMemsetAsync(bv, 0, (size_t)2 * TT * MII * 4, stream);
  for (int hf = 0; hf < 2; ++hf) {
    const float* w1p = We1 + (size_t)hf * 4 * DD * MII;
    cvt_wT<<<dim3(MII / 32, DD / 32, 4), 256, 0, stream>>>(w1p, wshi, NOU, DD, MII);
    gemm_bx2<1, 0, 2><<<dim3(8, 16, 8), 256, 0, stream>>>(
        hhi, NOU, DD, 0, wshi, NOU, (long)DD * MII, bu, NOU, NOU, MII, 0,
        0, MII, DD, blist, boff + 4 * hf, bcnt + 4 * hf, NOI, NOF);
  }
  for (int hf = 0; hf < 2; ++hf) {
    const float* w3p = We3 + (size_t)hf * 4 * DD * MII;
    cvt_wT<<<dim3(MII / 32, DD / 32, 4), 256, 0, stream>>>(w3p, wshi, NOU, DD, MII);
    gemm_bx2<1, 0, 2><<<dim3(8, 16, 8), 256, 0, stream>>>(
        hhi, NOU, DD, 0, wshi, NOU, (long)DD * MII, bv, NOU, NOU, MII, 0,
        0, MII, DD, blist, boff + 4 * hf, bcnt + 4 * hf, NOI, NOF);
  }
  silu_cvt<<<(2 * TT * MII) / 1024, 256, 0, stream>>>(bu, bv, uhi, (long)2 * TT * MII);
  for (int hf = 0; hf < 2; ++hf) {
    const float* w2p = We2 + (size_t)hf * 4 * MII * DD;
    cvt_wT<<<dim3(DD / 32, MII / 32, 4), 256, 0, stream>>>(w2p, wshi, NOU, MII, DD);
    gemm_bx2<1, 2><<<dim3(16, 16, 4), 256, 0, stream>>>(
        uhi, NOU, MII, 0, wshi, NOU, (long)MII * DD, outp, NOU, NOU, DD, 0,
        0, DD, MII, NOI, boff + 4 * hf, bcnt + 4 * hf, blist, bwlist);
  }
}